// Round 1
// baseline (1390.576 us; speedup 1.0000x reference)
//
#include <hip/hip_runtime.h>
#include <math.h>

#define Bd 2
#define Nd 2048
#define Cd 256
#define Ld 4
#define Hd 8
#define DHd 32
#define Md (Bd*Nd)   // 4096

// ---------------------------------------------------------------- pos embed
__global__ __launch_bounds__(256)
void pos_add_kernel(const float* __restrict__ xin, float* __restrict__ xout)
{
    int i = blockIdx.x * 256 + threadIdx.x;      // over M*C
    int c = i & (Cd - 1);
    int n = (i >> 8) & (Nd - 1);
    const float kneg = -9.210340371976184f / 256.0f;   // -ln(10000)/C
    float div = __expf((float)(c & ~1) * kneg);
    float ang = (float)n * div;
    float pe = (c & 1) ? cosf(ang) : sinf(ang);
    xout[i] = xin[i] + pe;
}

// ---------------------------------------------------------------- GEMM fp32
// out[M x Nout] = A[M x 256] @ W[256 x Nout] (+bias) (+gelu)
__global__ __launch_bounds__(256)
void gemm_kernel(const float* __restrict__ A, const float* __restrict__ W,
                 const float* __restrict__ bias, float* __restrict__ out,
                 int Nout, int act)
{
    __shared__ float As[16][65];
    __shared__ float Bs[16][65];
    int tid = threadIdx.x;
    int tx = tid & 15, ty = tid >> 4;
    int rowBase = blockIdx.y * 64;
    int colBase = blockIdx.x * 64;
    float acc[4][4] = {};

    int ra = tid >> 4;        // 0..15 (A row within 16-row group)
    int ck = tid & 15;        // A k-col
    int kb = tid >> 6;        // 0..3  (B k-row within 4-row group)
    int cb = tid & 63;        // B col

    for (int kt = 0; kt < 256; kt += 16) {
#pragma unroll
        for (int i = 0; i < 4; i++)
            As[ck][ra + 16 * i] = A[(size_t)(rowBase + ra + 16 * i) * 256 + kt + ck];
#pragma unroll
        for (int i = 0; i < 4; i++)
            Bs[kb + 4 * i][cb] = W[(size_t)(kt + kb + 4 * i) * Nout + colBase + cb];
        __syncthreads();
#pragma unroll
        for (int k = 0; k < 16; k++) {
            float a[4], b[4];
#pragma unroll
            for (int i = 0; i < 4; i++) a[i] = As[k][ty + 16 * i];
#pragma unroll
            for (int j = 0; j < 4; j++) b[j] = Bs[k][tx + 16 * j];
#pragma unroll
            for (int i = 0; i < 4; i++)
#pragma unroll
                for (int j = 0; j < 4; j++)
                    acc[i][j] += a[i] * b[j];
        }
        __syncthreads();
    }

#pragma unroll
    for (int i = 0; i < 4; i++) {
        int r = rowBase + ty + 16 * i;
#pragma unroll
        for (int j = 0; j < 4; j++) {
            int cc = colBase + tx + 16 * j;
            float v = acc[i][j];
            if (bias) v += bias[cc];
            if (act) v = 0.5f * v * (1.0f + erff(v * 0.7071067811865476f));
            out[(size_t)r * Nout + cc] = v;
        }
    }
}

// ---------------------------------------------------------------- attention
// qkv: [B, N, 768] rows = [q(256) k(256) v(256)], per-head 32 contiguous.
// grid: (N/32, B*H); block 256.  8 threads per q-row, online softmax.
#define KT 64
__global__ __launch_bounds__(256)
void attn_kernel(const float* __restrict__ qkv, float* __restrict__ out)
{
    __shared__ float Ks[KT * 36];
    __shared__ float Vs[KT * 36];
    int bh = blockIdx.y;
    int b = bh >> 3, h = bh & 7;
    int t = threadIdx.x;
    int row = t >> 3;          // 0..31
    int sub = t & 7;           // 0..7
    int qn = blockIdx.x * 32 + row;

    const float* qrow = qkv + (size_t)(b * Nd + qn) * 768 + h * 32;
    float q[32];
#pragma unroll
    for (int i = 0; i < 8; i++) {
        float4 v = *(const float4*)(qrow + i * 4);
        q[4 * i] = v.x; q[4 * i + 1] = v.y; q[4 * i + 2] = v.z; q[4 * i + 3] = v.w;
    }
    const float scale = 0.17677669529663687f;  // 1/sqrt(32)
    float m = -1e30f, l = 0.f;
    float acc[32];
#pragma unroll
    for (int d = 0; d < 32; d++) acc[d] = 0.f;

    for (int k0 = 0; k0 < Nd; k0 += KT) {
        // stage K,V tile (KT x 32) with stride-36 padding
        {
            int f = t * 8;
            int kr = f >> 5, d = f & 31;
            const float* kp = qkv + (size_t)(b * Nd + k0 + kr) * 768 + 256 + h * 32 + d;
            const float* vp = kp + 256;
            float4 a0 = *(const float4*)kp;
            float4 a1 = *(const float4*)(kp + 4);
            float4 b0 = *(const float4*)vp;
            float4 b1 = *(const float4*)(vp + 4);
            *(float4*)&Ks[kr * 36 + d] = a0; *(float4*)&Ks[kr * 36 + d + 4] = a1;
            *(float4*)&Vs[kr * 36 + d] = b0; *(float4*)&Vs[kr * 36 + d + 4] = b1;
        }
        __syncthreads();
        for (int kk = sub; kk < KT; kk += 8) {
            const float* krow = &Ks[kk * 36];
            float s = 0.f;
#pragma unroll
            for (int j = 0; j < 8; j++) {
                float4 kv = *(const float4*)(krow + 4 * j);
                s += q[4 * j] * kv.x + q[4 * j + 1] * kv.y
                   + q[4 * j + 2] * kv.z + q[4 * j + 3] * kv.w;
            }
            s *= scale;
            if (s > m) {
                float f = __expf(m - s);
                l *= f;
#pragma unroll
                for (int d = 0; d < 32; d++) acc[d] *= f;
                m = s;
            }
            float p = __expf(s - m);
            l += p;
            const float* vrow = &Vs[kk * 36];
#pragma unroll
            for (int j = 0; j < 8; j++) {
                float4 vv = *(const float4*)(vrow + 4 * j);
                acc[4 * j]     += p * vv.x;
                acc[4 * j + 1] += p * vv.y;
                acc[4 * j + 2] += p * vv.z;
                acc[4 * j + 3] += p * vv.w;
            }
        }
        __syncthreads();
    }

    // combine the 8 partials (lanes sub 0..7 within the wave)
#pragma unroll
    for (int off = 4; off >= 1; off >>= 1) {
        float om = __shfl_xor(m, off, 8);
        float ol = __shfl_xor(l, off, 8);
        float nm = fmaxf(m, om);
        float fs = __expf(m - nm), fo = __expf(om - nm);
        l = l * fs + ol * fo;
#pragma unroll
        for (int d = 0; d < 32; d++) {
            float oa = __shfl_xor(acc[d], off, 8);
            acc[d] = acc[d] * fs + oa * fo;
        }
        m = nm;
    }
    float inv = 1.0f / l;
    float* op = out + (size_t)(b * Nd + qn) * 256 + h * 32 + sub * 4;
    float4 r;
    r.x = acc[sub * 4] * inv;     r.y = acc[sub * 4 + 1] * inv;
    r.z = acc[sub * 4 + 2] * inv; r.w = acc[sub * 4 + 3] * inv;
    *(float4*)op = r;
}

// ---------------------------------------------------------------- residual+LN
// out_row = LN(x_row + r_row) * g + b ; one wave per row, 4 rows per block
__global__ __launch_bounds__(256)
void ln_kernel(const float* __restrict__ x, const float* __restrict__ r,
               const float* __restrict__ g, const float* __restrict__ be,
               float* __restrict__ out)
{
    int lane = threadIdx.x & 63;
    int w = threadIdx.x >> 6;
    int row = blockIdx.x * 4 + w;
    const float* xp = x + (size_t)row * 256 + lane * 4;
    const float* rp = r + (size_t)row * 256 + lane * 4;
    float4 a = *(const float4*)xp;
    float4 bb = *(const float4*)rp;
    float v0 = a.x + bb.x, v1 = a.y + bb.y, v2 = a.z + bb.z, v3 = a.w + bb.w;
    float s = v0 + v1 + v2 + v3;
#pragma unroll
    for (int off = 32; off >= 1; off >>= 1) s += __shfl_xor(s, off, 64);
    float mu = s * (1.0f / 256.0f);
    float d0 = v0 - mu, d1 = v1 - mu, d2 = v2 - mu, d3 = v3 - mu;
    float sq = d0 * d0 + d1 * d1 + d2 * d2 + d3 * d3;
#pragma unroll
    for (int off = 32; off >= 1; off >>= 1) sq += __shfl_xor(sq, off, 64);
    float rstd = rsqrtf(sq * (1.0f / 256.0f) + 1e-6f);
    float4 gg = *(const float4*)(g + lane * 4);
    float4 ee = *(const float4*)(be + lane * 4);
    float4 o;
    o.x = d0 * rstd * gg.x + ee.x;
    o.y = d1 * rstd * gg.y + ee.y;
    o.z = d2 * rstd * gg.z + ee.z;
    o.w = d3 * rstd * gg.w + ee.w;
    *(float4*)(out + (size_t)row * 256 + lane * 4) = o;
}

// ---------------------------------------------------------------- launch
extern "C" void kernel_launch(void* const* d_in, const int* in_sizes, int n_in,
                              void* d_out, int out_size, void* d_ws, size_t ws_size,
                              hipStream_t stream)
{
    const float* x_in   = (const float*)d_in[0];
    const float* qkv_w  = (const float*)d_in[1];
    const float* proj_w = (const float*)d_in[2];
    const float* proj_b = (const float*)d_in[3];
    const float* w1     = (const float*)d_in[4];
    const float* b1     = (const float*)d_in[5];
    const float* w2     = (const float*)d_in[6];
    const float* b2     = (const float*)d_in[7];
    const float* g1     = (const float*)d_in[8];
    const float* be1    = (const float*)d_in[9];
    const float* g2     = (const float*)d_in[10];
    const float* be2    = (const float*)d_in[11];
    float* outp = (float*)d_out;

    float* ws = (float*)d_ws;
    float* xbuf   = ws;                                // M*C
    float* qkvbuf = xbuf + (size_t)Md * Cd;            // M*768
    float* attno  = qkvbuf + (size_t)Md * 768;         // M*C
    float* tmp    = attno + (size_t)Md * Cd;           // M*C
    float* tmp2   = tmp + (size_t)Md * Cd;             // M*C

    pos_add_kernel<<<Md * Cd / 256, 256, 0, stream>>>(x_in, xbuf);

    for (int l = 0; l < Ld; l++) {
        const float* qw = qkv_w + (size_t)l * 256 * 768;
        const float* pw = proj_w + (size_t)l * 256 * 256;
        const float* pb = proj_b + (size_t)l * 256;
        const float* W1 = w1 + (size_t)l * 256 * 256;
        const float* B1 = b1 + (size_t)l * 256;
        const float* W2 = w2 + (size_t)l * 256 * 256;
        const float* B2 = b2 + (size_t)l * 256;

        gemm_kernel<<<dim3(768 / 64, Md / 64), 256, 0, stream>>>(
            xbuf, qw, nullptr, qkvbuf, 768, 0);
        attn_kernel<<<dim3(Nd / 32, Bd * Hd), 256, 0, stream>>>(qkvbuf, attno);
        gemm_kernel<<<dim3(256 / 64, Md / 64), 256, 0, stream>>>(
            attno, pw, pb, tmp, 256, 0);
        ln_kernel<<<Md / 4, 256, 0, stream>>>(xbuf, tmp, g1 + l * 256, be1 + l * 256, xbuf);
        gemm_kernel<<<dim3(256 / 64, Md / 64), 256, 0, stream>>>(
            xbuf, W1, B1, tmp, 256, 1);
        gemm_kernel<<<dim3(256 / 64, Md / 64), 256, 0, stream>>>(
            tmp, W2, B2, tmp2, 256, 0);
        ln_kernel<<<Md / 4, 256, 0, stream>>>(
            xbuf, tmp2, g2 + l * 256, be2 + l * 256, (l == Ld - 1) ? outp : xbuf);
    }
}

// Round 3
// 568.946 us; speedup vs baseline: 2.4441x; 2.4441x over previous
//
#include <hip/hip_runtime.h>
#include <math.h>

#define Bd 2
#define Nd 2048
#define Cd 256
#define Ld 4
#define Hd 8
#define Md (Bd*Nd)   // 4096

typedef __attribute__((ext_vector_type(8))) short bf16x8;
typedef __attribute__((ext_vector_type(4))) float f32x4;

static __device__ inline f32x4 mfma16(bf16x8 a, bf16x8 b, f32x4 c) {
    return __builtin_amdgcn_mfma_f32_16x16x32_bf16(a, b, c, 0, 0, 0);
}

static __device__ inline short f2bf(float f) {
    union { float f; unsigned u; } v; v.f = f;
    unsigned r = (v.u + 0x7fff + ((v.u >> 16) & 1)) >> 16;
    return (short)r;
}

// ---------------------------------------------------------------- pos embed
__global__ __launch_bounds__(256)
void pos_add_kernel(const float* __restrict__ xin, float* __restrict__ xout)
{
    int i = blockIdx.x * 256 + threadIdx.x;
    int c = i & (Cd - 1);
    int n = (i >> 8) & (Nd - 1);
    const float kneg = -9.210340371976184f / 256.0f;
    float div = __expf((float)(c & ~1) * kneg);
    float ang = (float)n * div;
    float pe = (c & 1) ? cosf(ang) : sinf(ang);
    xout[i] = xin[i] + pe;
}

// ---------------------------------------------------------------- bf16 MFMA GEMM
// out[M x Nout] = A[M x 256] @ W[256 x Nout] (+bias) (+gelu). fp32 in/out.
// 64x64 tile, 4 waves (2x2 of 32x32), K-chunk 64.
__global__ __launch_bounds__(256)
void gemm_bf16_kernel(const float* __restrict__ A, const float* __restrict__ W,
                      const float* __restrict__ bias, float* __restrict__ out,
                      int Nout, int act)
{
    __shared__ short As[64 * 72];   // A tile [row][k], pad 72
    __shared__ short Ws[64 * 72];   // W tile transposed [col][k], pad 72

    int t = threadIdx.x;
    int w = t >> 6, l = t & 63;
    int g = l >> 4, c = l & 15;
    int wr = w >> 1, wc = w & 1;
    int rowBase = blockIdx.y * 64, colBase = blockIdx.x * 64;

    const f32x4 zero = {0.f, 0.f, 0.f, 0.f};
    f32x4 acc[2][2];
#pragma unroll
    for (int m = 0; m < 2; m++)
#pragma unroll
        for (int n = 0; n < 2; n++) acc[m][n] = zero;

    int ar = t >> 2, cg = t & 3;       // A staging: row, 16-col group
    int scol = t & 63, sg = t >> 6;    // W staging: col, k-slot group

    for (int kt = 0; kt < 256; kt += 64) {
        // stage A (64x64 f32 -> bf16)
        {
            const float* ap = A + (size_t)(rowBase + ar) * 256 + kt + cg * 16;
            float av[16];
#pragma unroll
            for (int i = 0; i < 4; i++) {
                float4 v = *(const float4*)(ap + 4 * i);
                av[4 * i] = v.x; av[4 * i + 1] = v.y; av[4 * i + 2] = v.z; av[4 * i + 3] = v.w;
            }
            bf16x8 p0, p1;
#pragma unroll
            for (int j = 0; j < 8; j++) { p0[j] = f2bf(av[j]); p1[j] = f2bf(av[8 + j]); }
            *(bf16x8*)&As[ar * 72 + cg * 16] = p0;
            *(bf16x8*)&As[ar * 72 + cg * 16 + 8] = p1;
        }
        // stage W transposed (64x64): Ws[col][k]
        {
#pragma unroll
            for (int rep = 0; rep < 2; rep++) {
                int kbase = 32 * rep + 8 * sg;
                bf16x8 p;
#pragma unroll
                for (int j = 0; j < 8; j++)
                    p[j] = f2bf(W[(size_t)(kt + kbase + j) * Nout + colBase + scol]);
                *(bf16x8*)&Ws[scol * 72 + kbase] = p;
            }
        }
        __syncthreads();
#pragma unroll
        for (int ks = 0; ks < 2; ks++) {
            int kk = ks * 32 + 8 * g;
            bf16x8 a0 = *(bf16x8*)&As[(32 * wr + c) * 72 + kk];
            bf16x8 a1 = *(bf16x8*)&As[(32 * wr + 16 + c) * 72 + kk];
            bf16x8 b0 = *(bf16x8*)&Ws[(32 * wc + c) * 72 + kk];
            bf16x8 b1 = *(bf16x8*)&Ws[(32 * wc + 16 + c) * 72 + kk];
            acc[0][0] = mfma16(a0, b0, acc[0][0]);
            acc[0][1] = mfma16(a0, b1, acc[0][1]);
            acc[1][0] = mfma16(a1, b0, acc[1][0]);
            acc[1][1] = mfma16(a1, b1, acc[1][1]);
        }
        __syncthreads();
    }

#pragma unroll
    for (int m = 0; m < 2; m++)
#pragma unroll
        for (int n = 0; n < 2; n++)
#pragma unroll
            for (int r = 0; r < 4; r++) {
                int row = rowBase + 32 * wr + 16 * m + 4 * g + r;
                int col = colBase + 32 * wc + 16 * n + c;
                float v = acc[m][n][r];
                if (bias) v += bias[col];
                if (act) v = 0.5f * v * (1.0f + erff(v * 0.7071067811865476f));
                out[(size_t)row * Nout + col] = v;
            }
}

// ---------------------------------------------------------------- MFMA attention
// qkv: [B,N,768] rows = [q|k|v], head-dim 32 contiguous. Flash-style.
// grid (N/64, B*H), 4 waves; wave handles 16 q rows; 64-key tiles.
__global__ __launch_bounds__(256)
void attn_mfma_kernel(const float* __restrict__ qkv, float* __restrict__ out)
{
    __shared__ short Ks[64 * 40];        // K tile bf16 [key][dh], pad 40
    __shared__ short Vt[32 * 72];        // V tile bf16 transposed [dh][key], pad 72
    __shared__ float Ps[4][16 * 68];     // per-wave P f32 [q][key], pad 68

    int bh = blockIdx.y;
    int b = bh >> 3, h = bh & 7;
    int t = threadIdx.x;
    int w = t >> 6, l = t & 63;
    int g = l >> 4, c = l & 15;
    int q0 = blockIdx.x * 64 + w * 16;

    const float scale = 0.17677669529663687f;  // 1/sqrt(32)
    const f32x4 zero = {0.f, 0.f, 0.f, 0.f};

    // Q fragment: row=c, k=8g+j (scale folded in before bf16)
    bf16x8 qa;
    {
        const float* qp = qkv + (size_t)(b * Nd + q0 + c) * 768 + h * 32 + g * 8;
        float4 v0 = *(const float4*)qp;
        float4 v1 = *(const float4*)(qp + 4);
        float qv[8] = {v0.x, v0.y, v0.z, v0.w, v1.x, v1.y, v1.z, v1.w};
#pragma unroll
        for (int j = 0; j < 8; j++) qa[j] = f2bf(qv[j] * scale);
    }

    float m_[4], l_[4];
    f32x4 o0 = zero, o1 = zero;
#pragma unroll
    for (int r = 0; r < 4; r++) { m_[r] = -1e30f; l_[r] = 0.f; }

    for (int k0 = 0; k0 < Nd; k0 += 64) {
        // ---- stage K tile (bf16)
        {
            int key = t >> 2, qr = t & 3;
            const float* kp = qkv + (size_t)(b * Nd + k0 + key) * 768 + 256 + h * 32 + qr * 8;
            float4 v0 = *(const float4*)kp;
            float4 v1 = *(const float4*)(kp + 4);
            bf16x8 p;
            p[0] = f2bf(v0.x); p[1] = f2bf(v0.y); p[2] = f2bf(v0.z); p[3] = f2bf(v0.w);
            p[4] = f2bf(v1.x); p[5] = f2bf(v1.y); p[6] = f2bf(v1.z); p[7] = f2bf(v1.w);
            *(bf16x8*)&Ks[key * 40 + qr * 8] = p;
        }
        // ---- stage V transposed (bf16): Vt[dh][key]
        {
            int key0 = (t & 31) * 2;
            int dhb = (t >> 5) * 4;
            const float* vp0 = qkv + (size_t)(b * Nd + k0 + key0) * 768 + 512 + h * 32 + dhb;
            const float* vp1 = vp0 + 768;
            float4 v0 = *(const float4*)vp0;
            float4 v1 = *(const float4*)vp1;
            float a0[4] = {v0.x, v0.y, v0.z, v0.w};
            float a1[4] = {v1.x, v1.y, v1.z, v1.w};
#pragma unroll
            for (int j = 0; j < 4; j++) {
                unsigned u = ((unsigned)(unsigned short)f2bf(a0[j])) |
                             (((unsigned)(unsigned short)f2bf(a1[j])) << 16);
                *(unsigned*)&Vt[(dhb + j) * 72 + key0] = u;
            }
        }
        __syncthreads();

        // ---- QK^T: S[16q x 64k] as 4 fragments
        f32x4 s[4];
#pragma unroll
        for (int f = 0; f < 4; f++) {
            bf16x8 kb = *(bf16x8*)&Ks[(16 * f + c) * 40 + g * 8];
            s[f] = mfma16(qa, kb, zero);
        }

        // ---- online softmax (lane holds rows 4g+r, key cols 16f+c)
#pragma unroll
        for (int r = 0; r < 4; r++) {
            float tm = fmaxf(fmaxf(s[0][r], s[1][r]), fmaxf(s[2][r], s[3][r]));
#pragma unroll
            for (int off = 1; off <= 8; off <<= 1) tm = fmaxf(tm, __shfl_xor(tm, off, 64));
            float nm = fmaxf(m_[r], tm);
            float fr = __expf(m_[r] - nm);
            float p0 = __expf(s[0][r] - nm);
            float p1 = __expf(s[1][r] - nm);
            float p2 = __expf(s[2][r] - nm);
            float p3 = __expf(s[3][r] - nm);
            float* pr = &Ps[w][(4 * g + r) * 68 + c];
            pr[0] = p0; pr[16] = p1; pr[32] = p2; pr[48] = p3;
            float ts = p0 + p1 + p2 + p3;
#pragma unroll
            for (int off = 1; off <= 8; off <<= 1) ts += __shfl_xor(ts, off, 64);
            l_[r] = l_[r] * fr + ts;
            o0[r] *= fr; o1[r] *= fr;
            m_[r] = nm;
        }

        // make the per-wave P writes visible to this wave's reads
        asm volatile("s_waitcnt lgkmcnt(0)" ::: "memory");
        __builtin_amdgcn_sched_barrier(0);

        // ---- PV: O[16q x 32dh] += P[16x64] @ V[64x32]
#pragma unroll
        for (int ks = 0; ks < 2; ks++) {
            f32x4 pa0 = *(f32x4*)&Ps[w][c * 68 + ks * 32 + g * 8];
            f32x4 pa1 = *(f32x4*)&Ps[w][c * 68 + ks * 32 + g * 8 + 4];
            bf16x8 pa;
#pragma unroll
            for (int j = 0; j < 4; j++) { pa[j] = f2bf(pa0[j]); pa[4 + j] = f2bf(pa1[j]); }
            bf16x8 vb0 = *(bf16x8*)&Vt[c * 72 + ks * 32 + g * 8];
            bf16x8 vb1 = *(bf16x8*)&Vt[(16 + c) * 72 + ks * 32 + g * 8];
            o0 = mfma16(pa, vb0, o0);
            o1 = mfma16(pa, vb1, o1);
        }
        __syncthreads();
    }

    // ---- epilogue: normalize, write fp32
#pragma unroll
    for (int r = 0; r < 4; r++) {
        float inv = 1.0f / l_[r];
        int row = q0 + 4 * g + r;
        float* op = out + (size_t)(b * Nd + row) * 256 + h * 32;
        op[c] = o0[r] * inv;
        op[16 + c] = o1[r] * inv;
    }
}

// ---------------------------------------------------------------- residual+LN
__global__ __launch_bounds__(256)
void ln_kernel(const float* __restrict__ x, const float* __restrict__ r,
               const float* __restrict__ g, const float* __restrict__ be,
               float* __restrict__ out)
{
    int lane = threadIdx.x & 63;
    int w = threadIdx.x >> 6;
    int row = blockIdx.x * 4 + w;
    const float* xp = x + (size_t)row * 256 + lane * 4;
    const float* rp = r + (size_t)row * 256 + lane * 4;
    float4 a = *(const float4*)xp;
    float4 bb = *(const float4*)rp;
    float v0 = a.x + bb.x, v1 = a.y + bb.y, v2 = a.z + bb.z, v3 = a.w + bb.w;
    float s = v0 + v1 + v2 + v3;
#pragma unroll
    for (int off = 32; off >= 1; off >>= 1) s += __shfl_xor(s, off, 64);
    float mu = s * (1.0f / 256.0f);
    float d0 = v0 - mu, d1 = v1 - mu, d2 = v2 - mu, d3 = v3 - mu;
    float sq = d0 * d0 + d1 * d1 + d2 * d2 + d3 * d3;
#pragma unroll
    for (int off = 32; off >= 1; off >>= 1) sq += __shfl_xor(sq, off, 64);
    float rstd = rsqrtf(sq * (1.0f / 256.0f) + 1e-6f);
    float4 gg = *(const float4*)(g + lane * 4);
    float4 ee = *(const float4*)(be + lane * 4);
    float4 o;
    o.x = d0 * rstd * gg.x + ee.x;
    o.y = d1 * rstd * gg.y + ee.y;
    o.z = d2 * rstd * gg.z + ee.z;
    o.w = d3 * rstd * gg.w + ee.w;
    *(float4*)(out + (size_t)row * 256 + lane * 4) = o;
}

// ---------------------------------------------------------------- launch
extern "C" void kernel_launch(void* const* d_in, const int* in_sizes, int n_in,
                              void* d_out, int out_size, void* d_ws, size_t ws_size,
                              hipStream_t stream)
{
    const float* x_in   = (const float*)d_in[0];
    const float* qkv_w  = (const float*)d_in[1];
    const float* proj_w = (const float*)d_in[2];
    const float* proj_b = (const float*)d_in[3];
    const float* w1     = (const float*)d_in[4];
    const float* b1     = (const float*)d_in[5];
    const float* w2     = (const float*)d_in[6];
    const float* b2     = (const float*)d_in[7];
    const float* g1     = (const float*)d_in[8];
    const float* be1    = (const float*)d_in[9];
    const float* g2     = (const float*)d_in[10];
    const float* be2    = (const float*)d_in[11];
    float* outp = (float*)d_out;

    float* ws = (float*)d_ws;
    float* xbuf   = ws;                                // M*C
    float* qkvbuf = xbuf + (size_t)Md * Cd;            // M*768
    float* attno  = qkvbuf + (size_t)Md * 768;         // M*C
    float* tmp    = attno + (size_t)Md * Cd;           // M*C
    float* tmp2   = tmp + (size_t)Md * Cd;             // M*C

    pos_add_kernel<<<Md * Cd / 256, 256, 0, stream>>>(x_in, xbuf);

    for (int l = 0; l < Ld; l++) {
        const float* qw = qkv_w + (size_t)l * 256 * 768;
        const float* pw = proj_w + (size_t)l * 256 * 256;
        const float* pb = proj_b + (size_t)l * 256;
        const float* W1 = w1 + (size_t)l * 256 * 256;
        const float* B1 = b1 + (size_t)l * 256;
        const float* W2 = w2 + (size_t)l * 256 * 256;
        const float* B2 = b2 + (size_t)l * 256;

        gemm_bf16_kernel<<<dim3(768 / 64, Md / 64), 256, 0, stream>>>(
            xbuf, qw, nullptr, qkvbuf, 768, 0);
        attn_mfma_kernel<<<dim3(Nd / 64, Bd * Hd), 256, 0, stream>>>(qkvbuf, attno);
        gemm_bf16_kernel<<<dim3(256 / 64, Md / 64), 256, 0, stream>>>(
            attno, pw, pb, tmp, 256, 0);
        ln_kernel<<<Md / 4, 256, 0, stream>>>(xbuf, tmp, g1 + l * 256, be1 + l * 256, xbuf);
        gemm_bf16_kernel<<<dim3(256 / 64, Md / 64), 256, 0, stream>>>(
            xbuf, W1, B1, tmp, 256, 1);
        gemm_bf16_kernel<<<dim3(256 / 64, Md / 64), 256, 0, stream>>>(
            tmp, W2, B2, tmp2, 256, 0);
        ln_kernel<<<Md / 4, 256, 0, stream>>>(
            xbuf, tmp2, g2 + l * 256, be2 + l * 256, (l == Ld - 1) ? outp : xbuf);
    }
}

// Round 4
// 455.126 us; speedup vs baseline: 3.0554x; 1.2501x over previous
//
#include <hip/hip_runtime.h>
#include <math.h>

#define Bd 2
#define Nd 2048
#define Cd 256
#define Ld 4
#define Hd 8
#define Md (Bd*Nd)      // 4096
#define BHd 16
#define U32d 1024       // (B*H)*(N/32) units of 32 q-rows
#define SPLITd 4

typedef __attribute__((ext_vector_type(8))) short bf16x8;
typedef __attribute__((ext_vector_type(4))) float f32x4;
typedef __attribute__((ext_vector_type(4))) short shortx4;

static __device__ inline f32x4 mfma16(bf16x8 a, bf16x8 b, f32x4 c) {
    return __builtin_amdgcn_mfma_f32_16x16x32_bf16(a, b, c, 0, 0, 0);
}
static __device__ inline short f2bf(float f) {
    union { float f; unsigned u; } v; v.f = f;
    unsigned r = (v.u + 0x7fff + ((v.u >> 16) & 1)) >> 16;
    return (short)r;
}
static __device__ inline unsigned pkbf(float a, float b) {
    unsigned r;
    asm("v_cvt_pk_bf16_f32 %0, %1, %2" : "=v"(r) : "v"(a), "v"(b));
    return r;
}

// ------------------------------------------------ weight transpose + bf16
// src [L][256][Nc] f32 -> dst [L][Nc][256] bf16; cols < scaleLim get *scale
__global__ __launch_bounds__(256)
void wtrans_kernel(const float* __restrict__ src, short* __restrict__ dst,
                   int Nc, float scale, int scaleLim)
{
    __shared__ float tile[32][33];
    int l = blockIdx.z;
    src += (size_t)l * 256 * Nc;
    dst += (size_t)l * Nc * 256;
    int c0 = blockIdx.x * 32, k0 = blockIdx.y * 32;
    int tx = threadIdx.x & 31, ty = threadIdx.x >> 5;   // ty 0..7
#pragma unroll
    for (int i = 0; i < 4; i++) {
        int k = ty + 8 * i;
        tile[k][tx] = src[(size_t)(k0 + k) * Nc + c0 + tx];
    }
    __syncthreads();
#pragma unroll
    for (int i = 0; i < 4; i++) {
        int cc = ty + 8 * i;
        int col = c0 + cc;
        float v = tile[tx][cc];
        if (col < scaleLim) v *= scale;
        dst[(size_t)col * 256 + k0 + tx] = f2bf(v);
    }
}

// ------------------------------------------------ pos embed (dual out)
__global__ __launch_bounds__(256)
void pos_add_kernel(const float* __restrict__ xin, float* __restrict__ xf,
                    short* __restrict__ xb)
{
    int i = blockIdx.x * 256 + threadIdx.x;
    int c = i & (Cd - 1);
    int n = (i >> 8) & (Nd - 1);
    const float kneg = -9.210340371976184f / 256.0f;
    float div = __expf((float)(c & ~1) * kneg);
    float ang = (float)n * div;
    float pe = (c & 1) ? cosf(ang) : sinf(ang);
    float v = xin[i] + pe;
    xf[i] = v;
    xb[i] = f2bf(v);
}

// ------------------------------------------------ QKV GEMM (bf16, no LDS)
// A[M x 256] bf16 @ WT[768 x 256]^T -> Qb, Kb [B,N,256] bf16; Vtb [B*H,32,N] bf16
__global__ __launch_bounds__(256)
void qkv_gemm_kernel(const short* __restrict__ Ab, const short* __restrict__ WT,
                     short* __restrict__ Qb, short* __restrict__ Kb,
                     short* __restrict__ Vtb)
{
    int t = threadIdx.x, w = t >> 6, l = t & 63, c = l & 15, g = l >> 4;
    int rowBase = blockIdx.y * 128 + w * 32;
    int colBase = blockIdx.x * 32;
    const f32x4 zero = {0.f, 0.f, 0.f, 0.f};
    f32x4 acc[2][2] = {{zero, zero}, {zero, zero}};
    const short* ap0 = Ab + (size_t)(rowBase + c) * 256 + g * 8;
    const short* ap1 = ap0 + 16 * 256;
    const short* bp0 = WT + (size_t)(colBase + c) * 256 + g * 8;
    const short* bp1 = bp0 + 16 * 256;
#pragma unroll
    for (int kc = 0; kc < 256; kc += 32) {
        bf16x8 a0 = *(const bf16x8*)(ap0 + kc);
        bf16x8 a1 = *(const bf16x8*)(ap1 + kc);
        bf16x8 b0 = *(const bf16x8*)(bp0 + kc);
        bf16x8 b1 = *(const bf16x8*)(bp1 + kc);
        acc[0][0] = mfma16(a0, b0, acc[0][0]);
        acc[0][1] = mfma16(a0, b1, acc[0][1]);
        acc[1][0] = mfma16(a1, b0, acc[1][0]);
        acc[1][1] = mfma16(a1, b1, acc[1][1]);
    }
    int region = colBase >> 8;              // 0=Q 1=K 2=V (uniform per block)
    if (region < 2) {
        short* dst = (region == 0) ? Qb : Kb;
        int cb = colBase - region * 256;
#pragma unroll
        for (int m = 0; m < 2; m++)
#pragma unroll
            for (int n = 0; n < 2; n++)
#pragma unroll
                for (int r = 0; r < 4; r++)
                    dst[(size_t)(rowBase + 16 * m + 4 * g + r) * 256 + cb + 16 * n + c]
                        = f2bf(acc[m][n][r]);
    } else {
        int b = rowBase >> 11;
        int ntok0 = (rowBase & (Nd - 1)) + 4 * g;
#pragma unroll
        for (int m = 0; m < 2; m++)
#pragma unroll
            for (int n = 0; n < 2; n++) {
                int chg = colBase - 512 + 16 * n + c;        // h*32+chl
                shortx4 pkv;
#pragma unroll
                for (int r = 0; r < 4; r++) pkv[r] = f2bf(acc[m][n][r]);
                *(shortx4*)&Vtb[(size_t)((b * Hd + (chg >> 5)) * 32 + (chg & 31)) * Nd
                                + ntok0 + 16 * m] = pkv;
            }
    }
}

// ------------------------------------------------ attention partial (no barriers)
// 32 q-rows per wave, 4-way key split. Q pre-scaled by 1/sqrt(32)*log2(e).
__global__ __launch_bounds__(256)
void attn_part_kernel(const short* __restrict__ Qb, const short* __restrict__ Kb,
                      const short* __restrict__ Vtb, float* __restrict__ OP,
                      float* __restrict__ ML)
{
    __shared__ unsigned Plds[4 * 64 * 18];
    int t = threadIdx.x, w = t >> 6, l = t & 63, c = l & 15, g = l >> 4;
    int qt = blockIdx.x * 4 + w;         // 0..63 (32-row q tile)
    int bh = blockIdx.y, part = blockIdx.z;
    int b = bh >> 3, h = bh & 7;
    const f32x4 zero = {0.f, 0.f, 0.f, 0.f};

    bf16x8 qa[2];
#pragma unroll
    for (int qf = 0; qf < 2; qf++)
        qa[qf] = *(const bf16x8*)(Qb + (size_t)(b * Nd + qt * 32 + qf * 16 + c) * 256
                                  + h * 32 + g * 8);
    const short* kp = Kb + (size_t)b * Nd * 256 + h * 32 + g * 8;
    const short* vp = Vtb + (size_t)(bh * 32 + c) * Nd + g * 8;

    float m_[2] = {-1e30f, -1e30f}, l_[2] = {0.f, 0.f};
    f32x4 o_[2][2] = {{zero, zero}, {zero, zero}};

    int wb = w * 64 * 18;
    int myS = wb + l * 18;
    int srcA = wb + (c + 16 * ((2 * g) & 3)) * 18;
    int srcB = wb + (c + 16 * ((2 * g + 1) & 3)) * 18;
    int fhi = g >> 1;

    for (int k0 = part * (Nd / SPLITd); k0 < (part + 1) * (Nd / SPLITd); k0 += 64) {
        bf16x8 kf[4];
#pragma unroll
        for (int f = 0; f < 4; f++)
            kf[f] = *(const bf16x8*)(kp + (size_t)(k0 + 16 * f + c) * 256);
        bf16x8 vv[2][2];
#pragma unroll
        for (int ks = 0; ks < 2; ks++)
#pragma unroll
            for (int o = 0; o < 2; o++)
                vv[ks][o] = *(const bf16x8*)(vp + (size_t)(16 * o) * Nd + k0 + 32 * ks);

#pragma unroll
        for (int qf = 0; qf < 2; qf++) {
            f32x4 s[4];
#pragma unroll
            for (int f = 0; f < 4; f++) s[f] = mfma16(kf[f], qa[qf], zero);
            float mx = s[0][0];
#pragma unroll
            for (int f = 0; f < 4; f++)
#pragma unroll
                for (int r = 0; r < 4; r++) mx = fmaxf(mx, s[f][r]);
            mx = fmaxf(mx, __shfl_xor(mx, 16, 64));
            mx = fmaxf(mx, __shfl_xor(mx, 32, 64));
            float nm = m_[qf];
            if (!__all(mx <= nm)) {                 // wave-uniform
                nm = fmaxf(nm, mx);
                float fr = exp2f(m_[qf] - nm);
                l_[qf] *= fr;
#pragma unroll
                for (int r = 0; r < 4; r++) {
                    float fq = __shfl(fr, 4 * g + r, 64);
                    o_[qf][0][r] *= fq;
                    o_[qf][1][r] *= fq;
                }
                m_[qf] = nm;
            }
            float ps = 0.f;
#pragma unroll
            for (int f = 0; f < 4; f++)
#pragma unroll
                for (int r = 0; r < 4; r++) {
                    s[f][r] = exp2f(s[f][r] - nm);
                    ps += s[f][r];
                }
            ps += __shfl_xor(ps, 16, 64);
            ps += __shfl_xor(ps, 32, 64);
            l_[qf] += ps;
            uint2* wr = (uint2*)&Plds[myS + qf * 8];
#pragma unroll
            for (int f = 0; f < 4; f++)
                wr[f] = make_uint2(pkbf(s[f][0], s[f][1]), pkbf(s[f][2], s[f][3]));
        }

        asm volatile("s_waitcnt lgkmcnt(0)" ::: "memory");
        __builtin_amdgcn_sched_barrier(0);

#pragma unroll
        for (int qf = 0; qf < 2; qf++)
#pragma unroll
            for (int ks = 0; ks < 2; ks++) {
                int fd = 2 * ks + fhi;
                uint2 ra = *(const uint2*)&Plds[srcA + qf * 8 + fd * 2];
                uint2 rb = *(const uint2*)&Plds[srcB + qf * 8 + fd * 2];
                union { unsigned u[4]; bf16x8 v; } pa;
                pa.u[0] = ra.x; pa.u[1] = ra.y; pa.u[2] = rb.x; pa.u[3] = rb.y;
                o_[qf][0] = mfma16(pa.v, vv[ks][0], o_[qf][0]);
                o_[qf][1] = mfma16(pa.v, vv[ks][1], o_[qf][1]);
            }
    }

    int u = bh * 64 + qt;
    float* op = OP + ((size_t)part * U32d + u) * 1024;
#pragma unroll
    for (int qf = 0; qf < 2; qf++)
#pragma unroll
        for (int r = 0; r < 4; r++) {
            op[(qf * 16 + 4 * g + r) * 32 + c] = o_[qf][0][r];
            op[(qf * 16 + 4 * g + r) * 32 + 16 + c] = o_[qf][1][r];
        }
    if (g == 0) {
        float* mlp = ML + ((size_t)part * U32d + u) * 64;
#pragma unroll
        for (int qf = 0; qf < 2; qf++) {
            mlp[qf * 16 + c] = m_[qf];
            mlp[32 + qf * 16 + c] = l_[qf];
        }
    }
}

// ------------------------------------------------ attention combine
__global__ __launch_bounds__(256)
void attn_combine_kernel(const float* __restrict__ OP, const float* __restrict__ ML,
                         short* __restrict__ attb)
{
    int u = blockIdx.x;
    int bh = u >> 6, qt = u & 63;
    int b = bh >> 3, h = bh & 7;
    int t = threadIdx.x;
    int dh = t & 31, qr = t >> 5;
#pragma unroll
    for (int qq = 0; qq < 4; qq++) {
        int q = qr + 8 * qq;
        float m[SPLITd], lv[SPLITd];
        float M = -1e30f;
#pragma unroll
        for (int p = 0; p < SPLITd; p++) {
            m[p] = ML[((size_t)p * U32d + u) * 64 + q];
            lv[p] = ML[((size_t)p * U32d + u) * 64 + 32 + q];
            M = fmaxf(M, m[p]);
        }
        float L = 0.f, o = 0.f;
#pragma unroll
        for (int p = 0; p < SPLITd; p++) {
            float e = exp2f(m[p] - M);
            L += lv[p] * e;
            o += OP[((size_t)p * U32d + u) * 1024 + q * 32 + dh] * e;
        }
        attb[(size_t)(b * Nd + qt * 32 + q) * 256 + h * 32 + dh] = f2bf(o / L);
    }
}

// ------------------------------------------------ small GEMM (bf16, no LDS)
// MODE 0: f32 out + bias ; MODE 1: bf16 out + bias + exact GELU
template<int MODE>
__global__ __launch_bounds__(256)
void gemm_small_kernel(const short* __restrict__ Ab, const short* __restrict__ WT,
                       const float* __restrict__ bias, void* __restrict__ outv)
{
    int t = threadIdx.x, w = t >> 6, l = t & 63, c = l & 15, g = l >> 4;
    int rowBase = blockIdx.y * 64 + w * 16;
    int colBase = blockIdx.x * 32;
    const f32x4 zero = {0.f, 0.f, 0.f, 0.f};
    f32x4 acc0 = zero, acc1 = zero;
    const short* ap = Ab + (size_t)(rowBase + c) * 256 + g * 8;
    const short* bp0 = WT + (size_t)(colBase + c) * 256 + g * 8;
    const short* bp1 = bp0 + 16 * 256;
#pragma unroll
    for (int kc = 0; kc < 256; kc += 32) {
        bf16x8 a = *(const bf16x8*)(ap + kc);
        bf16x8 b0 = *(const bf16x8*)(bp0 + kc);
        bf16x8 b1 = *(const bf16x8*)(bp1 + kc);
        acc0 = mfma16(a, b0, acc0);
        acc1 = mfma16(a, b1, acc1);
    }
    float bi0 = bias[colBase + c], bi1 = bias[colBase + 16 + c];
#pragma unroll
    for (int r = 0; r < 4; r++) {
        int row = rowBase + 4 * g + r;
        float v0 = acc0[r] + bi0, v1 = acc1[r] + bi1;
        if (MODE == 1) {
            v0 = 0.5f * v0 * (1.f + erff(v0 * 0.7071067811865476f));
            v1 = 0.5f * v1 * (1.f + erff(v1 * 0.7071067811865476f));
        }
        if (MODE == 0) {
            float* o = (float*)outv + (size_t)row * 256 + colBase;
            o[c] = v0; o[16 + c] = v1;
        } else {
            short* o = (short*)outv + (size_t)row * 256 + colBase;
            o[c] = f2bf(v0); o[16 + c] = f2bf(v1);
        }
    }
}

// ------------------------------------------------ residual + LN (dual out)
__global__ __launch_bounds__(256)
void ln_dual_kernel(const float* __restrict__ x, const float* __restrict__ rsd,
                    const float* __restrict__ gg, const float* __restrict__ be,
                    float* __restrict__ outf, short* __restrict__ outb)
{
    int lane = threadIdx.x & 63;
    int w = threadIdx.x >> 6;
    int row = blockIdx.x * 4 + w;
    size_t off = (size_t)row * 256 + lane * 4;
    float4 a = *(const float4*)(x + off);
    float4 bb = *(const float4*)(rsd + off);
    float v0 = a.x + bb.x, v1 = a.y + bb.y, v2 = a.z + bb.z, v3 = a.w + bb.w;
    float s = v0 + v1 + v2 + v3;
#pragma unroll
    for (int o = 32; o >= 1; o >>= 1) s += __shfl_xor(s, o, 64);
    float mu = s * (1.0f / 256.0f);
    float d0 = v0 - mu, d1 = v1 - mu, d2 = v2 - mu, d3 = v3 - mu;
    float sq = d0 * d0 + d1 * d1 + d2 * d2 + d3 * d3;
#pragma unroll
    for (int o = 32; o >= 1; o >>= 1) sq += __shfl_xor(sq, o, 64);
    float rstd = rsqrtf(sq * (1.0f / 256.0f) + 1e-6f);
    float4 g4 = *(const float4*)(gg + lane * 4);
    float4 e4 = *(const float4*)(be + lane * 4);
    float4 o4;
    o4.x = d0 * rstd * g4.x + e4.x;
    o4.y = d1 * rstd * g4.y + e4.y;
    o4.z = d2 * rstd * g4.z + e4.z;
    o4.w = d3 * rstd * g4.w + e4.w;
    *(float4*)(outf + off) = o4;
    shortx4 ob;
    ob[0] = f2bf(o4.x); ob[1] = f2bf(o4.y); ob[2] = f2bf(o4.z); ob[3] = f2bf(o4.w);
    *(shortx4*)(outb + off) = ob;
}

// ------------------------------------------------ launch
extern "C" void kernel_launch(void* const* d_in, const int* in_sizes, int n_in,
                              void* d_out, int out_size, void* d_ws, size_t ws_size,
                              hipStream_t stream)
{
    const float* x_in   = (const float*)d_in[0];
    const float* qkv_w  = (const float*)d_in[1];
    const float* proj_w = (const float*)d_in[2];
    const float* proj_b = (const float*)d_in[3];
    const float* w1     = (const float*)d_in[4];
    const float* b1     = (const float*)d_in[5];
    const float* w2     = (const float*)d_in[6];
    const float* b2     = (const float*)d_in[7];
    const float* g1     = (const float*)d_in[8];
    const float* be1    = (const float*)d_in[9];
    const float* g2     = (const float*)d_in[10];
    const float* be2    = (const float*)d_in[11];
    float* outp = (float*)d_out;

    char* p = (char*)d_ws;
    float* xf   = (float*)p;  p += (size_t)Md * Cd * 4;
    short* xb   = (short*)p;  p += (size_t)Md * Cd * 2;
    short* Qb   = (short*)p;  p += (size_t)Md * Cd * 2;
    short* Kb   = (short*)p;  p += (size_t)Md * Cd * 2;
    short* Vtb  = (short*)p;  p += (size_t)Md * Cd * 2;
    short* attb = (short*)p;  p += (size_t)Md * Cd * 2;   // aliased: fc1 out
    short* fc1b = attb;
    float* OP   = (float*)p;                              // aliased: tmp
    float* tmp  = OP;         p += (size_t)SPLITd * U32d * 1024 * 4;
    float* ML   = (float*)p;  p += (size_t)SPLITd * U32d * 64 * 4;
    short* qkvT = (short*)p;  p += (size_t)Ld * 768 * 256 * 2;
    short* projT= (short*)p;  p += (size_t)Ld * 256 * 256 * 2;
    short* w1T  = (short*)p;  p += (size_t)Ld * 256 * 256 * 2;
    short* w2T  = (short*)p;  p += (size_t)Ld * 256 * 256 * 2;

    const float QSCALE = 0.17677669529663687f * 1.4426950408889634f; // 1/sqrt(32)*log2e
    wtrans_kernel<<<dim3(24, 8, Ld), 256, 0, stream>>>(qkv_w, qkvT, 768, QSCALE, 256);
    wtrans_kernel<<<dim3(8, 8, Ld), 256, 0, stream>>>(proj_w, projT, 256, 1.f, 0);
    wtrans_kernel<<<dim3(8, 8, Ld), 256, 0, stream>>>(w1, w1T, 256, 1.f, 0);
    wtrans_kernel<<<dim3(8, 8, Ld), 256, 0, stream>>>(w2, w2T, 256, 1.f, 0);
    pos_add_kernel<<<Md * Cd / 256, 256, 0, stream>>>(x_in, xf, xb);

    for (int l = 0; l < Ld; l++) {
        qkv_gemm_kernel<<<dim3(24, 32), 256, 0, stream>>>(
            xb, qkvT + (size_t)l * 768 * 256, Qb, Kb, Vtb);
        attn_part_kernel<<<dim3(16, BHd, SPLITd), 256, 0, stream>>>(Qb, Kb, Vtb, OP, ML);
        attn_combine_kernel<<<U32d, 256, 0, stream>>>(OP, ML, attb);
        gemm_small_kernel<0><<<dim3(8, 64), 256, 0, stream>>>(
            attb, projT + (size_t)l * 65536, proj_b + l * 256, tmp);
        ln_dual_kernel<<<Md / 4, 256, 0, stream>>>(
            xf, tmp, g1 + l * 256, be1 + l * 256, xf, xb);
        gemm_small_kernel<1><<<dim3(8, 64), 256, 0, stream>>>(
            xb, w1T + (size_t)l * 65536, b1 + l * 256, fc1b);
        gemm_small_kernel<0><<<dim3(8, 64), 256, 0, stream>>>(
            fc1b, w2T + (size_t)l * 65536, b2 + l * 256, tmp);
        ln_dual_kernel<<<Md / 4, 256, 0, stream>>>(
            xf, tmp, g2 + l * 256, be2 + l * 256, (l == Ld - 1) ? outp : xf, xb);
    }
}

// Round 5
// 400.351 us; speedup vs baseline: 3.4734x; 1.1368x over previous
//
#include <hip/hip_runtime.h>
#include <math.h>

#define Bd 2
#define Nd 2048
#define Cd 256
#define Ld 4
#define Hd 8
#define Md (Bd*Nd)      // 4096
#define BHd 16
#define U32d 1024       // (B*H)*(N/32) units of 32 q-rows
#define SPLITd 4

typedef __attribute__((ext_vector_type(8))) short bf16x8;
typedef __attribute__((ext_vector_type(4))) float f32x4;
typedef __attribute__((ext_vector_type(16))) float f32x16;
typedef __attribute__((ext_vector_type(4))) short shortx4;

static __device__ inline f32x4 mfma16(bf16x8 a, bf16x8 b, f32x4 c) {
    return __builtin_amdgcn_mfma_f32_16x16x32_bf16(a, b, c, 0, 0, 0);
}
static __device__ inline f32x16 mfma32(bf16x8 a, bf16x8 b, f32x16 c) {
    return __builtin_amdgcn_mfma_f32_32x32x16_bf16(a, b, c, 0, 0, 0);
}
static __device__ inline short f2bf(float f) {
    union { float f; unsigned u; } v; v.f = f;
    unsigned r = (v.u + 0x7fff + ((v.u >> 16) & 1)) >> 16;
    return (short)r;
}
static __device__ inline unsigned pkbf(float a, float b) {
    unsigned r;
    asm("v_cvt_pk_bf16_f32 %0, %1, %2" : "=v"(r) : "v"(a), "v"(b));
    return r;
}

// ------------------------------------------------ weight transpose + bf16
// src [L][256][Nc] f32 -> dst [L][Nc][256] bf16; cols < scaleLim get *scale
__global__ __launch_bounds__(256)
void wtrans_kernel(const float* __restrict__ src, short* __restrict__ dst,
                   int Nc, float scale, int scaleLim)
{
    __shared__ float tile[32][33];
    int l = blockIdx.z;
    src += (size_t)l * 256 * Nc;
    dst += (size_t)l * Nc * 256;
    int c0 = blockIdx.x * 32, k0 = blockIdx.y * 32;
    int tx = threadIdx.x & 31, ty = threadIdx.x >> 5;   // ty 0..7
#pragma unroll
    for (int i = 0; i < 4; i++) {
        int k = ty + 8 * i;
        tile[k][tx] = src[(size_t)(k0 + k) * Nc + c0 + tx];
    }
    __syncthreads();
#pragma unroll
    for (int i = 0; i < 4; i++) {
        int cc = ty + 8 * i;
        int col = c0 + cc;
        float v = tile[tx][cc];
        if (col < scaleLim) v *= scale;
        dst[(size_t)col * 256 + k0 + tx] = f2bf(v);
    }
}

// ------------------------------------------------ pos embed (dual out)
__global__ __launch_bounds__(256)
void pos_add_kernel(const float* __restrict__ xin, float* __restrict__ xf,
                    short* __restrict__ xb)
{
    int i = blockIdx.x * 256 + threadIdx.x;
    int c = i & (Cd - 1);
    int n = (i >> 8) & (Nd - 1);
    const float kneg = -9.210340371976184f / 256.0f;
    float div = __expf((float)(c & ~1) * kneg);
    float ang = (float)n * div;
    float pe = (c & 1) ? cosf(ang) : sinf(ang);
    float v = xin[i] + pe;
    xf[i] = v;
    xb[i] = f2bf(v);
}

// ------------------------------------------------ QKV GEMM (bf16, no LDS)
__global__ __launch_bounds__(256)
void qkv_gemm_kernel(const short* __restrict__ Ab, const short* __restrict__ WT,
                     short* __restrict__ Qb, short* __restrict__ Kb,
                     short* __restrict__ Vtb)
{
    int t = threadIdx.x, w = t >> 6, l = t & 63, c = l & 15, g = l >> 4;
    int rowBase = blockIdx.y * 128 + w * 32;
    int colBase = blockIdx.x * 32;
    const f32x4 zero = {0.f, 0.f, 0.f, 0.f};
    f32x4 acc[2][2] = {{zero, zero}, {zero, zero}};
    const short* ap0 = Ab + (size_t)(rowBase + c) * 256 + g * 8;
    const short* ap1 = ap0 + 16 * 256;
    const short* bp0 = WT + (size_t)(colBase + c) * 256 + g * 8;
    const short* bp1 = bp0 + 16 * 256;
#pragma unroll
    for (int kc = 0; kc < 256; kc += 32) {
        bf16x8 a0 = *(const bf16x8*)(ap0 + kc);
        bf16x8 a1 = *(const bf16x8*)(ap1 + kc);
        bf16x8 b0 = *(const bf16x8*)(bp0 + kc);
        bf16x8 b1 = *(const bf16x8*)(bp1 + kc);
        acc[0][0] = mfma16(a0, b0, acc[0][0]);
        acc[0][1] = mfma16(a0, b1, acc[0][1]);
        acc[1][0] = mfma16(a1, b0, acc[1][0]);
        acc[1][1] = mfma16(a1, b1, acc[1][1]);
    }
    int region = colBase >> 8;              // 0=Q 1=K 2=V (uniform per block)
    if (region < 2) {
        short* dst = (region == 0) ? Qb : Kb;
        int cb = colBase - region * 256;
#pragma unroll
        for (int m = 0; m < 2; m++)
#pragma unroll
            for (int n = 0; n < 2; n++)
#pragma unroll
                for (int r = 0; r < 4; r++)
                    dst[(size_t)(rowBase + 16 * m + 4 * g + r) * 256 + cb + 16 * n + c]
                        = f2bf(acc[m][n][r]);
    } else {
        int b = rowBase >> 11;
        int ntok0 = (rowBase & (Nd - 1)) + 4 * g;
#pragma unroll
        for (int m = 0; m < 2; m++)
#pragma unroll
            for (int n = 0; n < 2; n++) {
                int chg = colBase - 512 + 16 * n + c;        // h*32+chl
                shortx4 pkv;
#pragma unroll
                for (int r = 0; r < 4; r++) pkv[r] = f2bf(acc[m][n][r]);
                *(shortx4*)&Vtb[(size_t)((b * Hd + (chg >> 5)) * 32 + (chg & 31)) * Nd
                                + ntok0 + 16 * m] = pkv;
            }
    }
}

// ------------------------------------------------ attention partial
// 32x32 MFMA, fixed-max softmax (exp2 direct), no LDS, no barriers.
// wave: 32 q-rows, 64-key tiles. Q pre-scaled by 1/sqrt(32)*log2(e).
__global__ __launch_bounds__(256)
void attn_part_kernel(const short* __restrict__ Qb, const short* __restrict__ Kb,
                      const short* __restrict__ Vtb, float* __restrict__ OP,
                      float* __restrict__ Lsum)
{
    int t = threadIdx.x, w = t >> 6, l = t & 63;
    int l5 = l >> 5, q32 = l & 31;
    bool low = (l5 == 0);
    int qt = blockIdx.x * 4 + w;
    int bh = blockIdx.y, part = blockIdx.z;
    int b = bh >> 3, h = bh & 7;

    bf16x8 qf0, qf1;
    {
        const short* qp = Qb + ((size_t)(b * Nd + qt * 32 + q32)) * 256 + h * 32 + 8 * l5;
        qf0 = *(const bf16x8*)qp;
        qf1 = *(const bf16x8*)(qp + 16);
    }
    const short* kp = Kb + (size_t)b * Nd * 256 + h * 32 + 8 * l5;
    const short* vp = Vtb + (size_t)(bh * 32 + q32) * Nd + 8 * l5;

    f32x16 O;
#pragma unroll
    for (int i = 0; i < 16; i++) O[i] = 0.f;
    float lsum = 0.f;

    for (int k0 = part * (Nd / SPLITd); k0 < (part + 1) * (Nd / SPLITd); k0 += 64) {
        bf16x8 kf[2][2], vv[4];
#pragma unroll
        for (int sb = 0; sb < 2; sb++)
#pragma unroll
            for (int ks = 0; ks < 2; ks++)
                kf[sb][ks] = *(const bf16x8*)(kp + (size_t)(k0 + 32 * sb + q32) * 256 + 16 * ks);
#pragma unroll
        for (int kc = 0; kc < 4; kc++)
            vv[kc] = *(const bf16x8*)(vp + k0 + 16 * kc);

#pragma unroll
        for (int sb = 0; sb < 2; sb++) {
            f32x16 s;
#pragma unroll
            for (int i = 0; i < 16; i++) s[i] = 0.f;
            s = mfma32(kf[sb][0], qf0, s);
            s = mfma32(kf[sb][1], qf1, s);
            float ps = 0.f;
#pragma unroll
            for (int i = 0; i < 16; i++) { s[i] = exp2f(s[i]); ps += s[i]; }
            ps += __shfl_xor(ps, 32, 64);
            lsum += ps;
            unsigned wd[8];
#pragma unroll
            for (int i = 0; i < 8; i++) wd[i] = pkbf(s[2 * i], s[2 * i + 1]);
#pragma unroll
            for (int half = 0; half < 2; half++) {
                int b0 = 4 * half;
                unsigned sx0 = (unsigned)__shfl_xor((int)wd[b0], 32, 64);
                unsigned sx1 = (unsigned)__shfl_xor((int)wd[b0 + 1], 32, 64);
                unsigned sx2 = (unsigned)__shfl_xor((int)wd[b0 + 2], 32, 64);
                unsigned sx3 = (unsigned)__shfl_xor((int)wd[b0 + 3], 32, 64);
                union { unsigned u[4]; bf16x8 v; } pa;
                pa.u[0] = low ? wd[b0] : sx2;
                pa.u[1] = low ? wd[b0 + 1] : sx3;
                pa.u[2] = low ? sx0 : wd[b0 + 2];
                pa.u[3] = low ? sx1 : wd[b0 + 3];
                O = mfma32(pa.v, vv[2 * sb + half], O);
            }
        }
    }

    int u = bh * 64 + qt;
    float* op = OP + ((size_t)part * U32d + u) * 1024;
#pragma unroll
    for (int i = 0; i < 16; i++) {
        int q = (i & 3) + 8 * (i >> 2) + 4 * l5;
        op[q * 32 + q32] = O[i];
    }
    if (low) Lsum[((size_t)part * U32d + u) * 32 + q32] = lsum;
}

// ------------------------------------------------ attention combine (plain sums)
__global__ __launch_bounds__(256)
void attn_combine_kernel(const float* __restrict__ OP, const float* __restrict__ Lsum,
                         short* __restrict__ attb)
{
    int u = blockIdx.x;
    int bh = u >> 6, qt = u & 63;
    int b = bh >> 3, h = bh & 7;
    int t = threadIdx.x;
    int dh = t & 31, qr = t >> 5;
#pragma unroll
    for (int qq = 0; qq < 4; qq++) {
        int q = qr + 8 * qq;
        float o = 0.f, L = 0.f;
#pragma unroll
        for (int p = 0; p < SPLITd; p++) {
            o += OP[((size_t)p * U32d + u) * 1024 + q * 32 + dh];
            L += Lsum[((size_t)p * U32d + u) * 32 + q];
        }
        attb[(size_t)(b * Nd + qt * 32 + q) * 256 + h * 32 + dh] = f2bf(o / L);
    }
}

// ------------------------------------------------ GEMM + bias + residual + LN (fused)
// block: 16 rows x 256 cols, 4 waves (64 cols each). grid = M/16.
template<int LAST>
__global__ __launch_bounds__(256)
void gemm_ln_kernel(const short* __restrict__ Ab, const short* __restrict__ WT,
                    const float* __restrict__ bias, const float* __restrict__ resid,
                    const float* __restrict__ gg, const float* __restrict__ be,
                    float* __restrict__ outf, short* __restrict__ outb)
{
    __shared__ float red[4][16][2];
    int t = threadIdx.x, w = t >> 6, l = t & 63, c = l & 15, g = l >> 4;
    int rowBase = blockIdx.x * 16;
    const f32x4 zero = {0.f, 0.f, 0.f, 0.f};
    f32x4 acc[4] = {zero, zero, zero, zero};
    const short* ap = Ab + (size_t)(rowBase + c) * 256 + g * 8;
    const short* bp = WT + (size_t)(w * 64 + c) * 256 + g * 8;
#pragma unroll
    for (int kc = 0; kc < 256; kc += 32) {
        bf16x8 a = *(const bf16x8*)(ap + kc);
#pragma unroll
        for (int n = 0; n < 4; n++)
            acc[n] = mfma16(a, *(const bf16x8*)(bp + n * 16 * 256 + kc), acc[n]);
    }
    float vv[4][4], s_[4] = {0.f, 0.f, 0.f, 0.f}, sq_[4] = {0.f, 0.f, 0.f, 0.f};
#pragma unroll
    for (int n = 0; n < 4; n++) {
        int col = w * 64 + 16 * n + c;
        float bi = bias[col];
#pragma unroll
        for (int r = 0; r < 4; r++) {
            int row = rowBase + 4 * g + r;
            float v = acc[n][r] + bi + resid[(size_t)row * 256 + col];
            vv[n][r] = v; s_[r] += v; sq_[r] += v * v;
        }
    }
#pragma unroll
    for (int off = 1; off <= 8; off <<= 1)
#pragma unroll
        for (int r = 0; r < 4; r++) {
            s_[r] += __shfl_xor(s_[r], off, 64);
            sq_[r] += __shfl_xor(sq_[r], off, 64);
        }
    if (c == 0)
#pragma unroll
        for (int r = 0; r < 4; r++) {
            red[w][4 * g + r][0] = s_[r];
            red[w][4 * g + r][1] = sq_[r];
        }
    __syncthreads();
    float mu[4], rs[4];
#pragma unroll
    for (int r = 0; r < 4; r++) {
        float S = 0.f, Q = 0.f;
#pragma unroll
        for (int ww = 0; ww < 4; ww++) { S += red[ww][4 * g + r][0]; Q += red[ww][4 * g + r][1]; }
        mu[r] = S * (1.f / 256.f);
        rs[r] = rsqrtf(Q * (1.f / 256.f) - mu[r] * mu[r] + 1e-6f);
    }
#pragma unroll
    for (int n = 0; n < 4; n++) {
        int col = w * 64 + 16 * n + c;
        float gv = gg[col], bv = be[col];
#pragma unroll
        for (int r = 0; r < 4; r++) {
            int row = rowBase + 4 * g + r;
            float o = (vv[n][r] - mu[r]) * rs[r] * gv + bv;
            outf[(size_t)row * 256 + col] = o;
            if (!LAST) outb[(size_t)row * 256 + col] = f2bf(o);
        }
    }
}

// ------------------------------------------------ small GEMM (fc1: bias+GELU->bf16)
__global__ __launch_bounds__(256)
void gemm_gelu_kernel(const short* __restrict__ Ab, const short* __restrict__ WT,
                      const float* __restrict__ bias, short* __restrict__ outb)
{
    int t = threadIdx.x, w = t >> 6, l = t & 63, c = l & 15, g = l >> 4;
    int rowBase = blockIdx.y * 64 + w * 16;
    int colBase = blockIdx.x * 32;
    const f32x4 zero = {0.f, 0.f, 0.f, 0.f};
    f32x4 acc0 = zero, acc1 = zero;
    const short* ap = Ab + (size_t)(rowBase + c) * 256 + g * 8;
    const short* bp0 = WT + (size_t)(colBase + c) * 256 + g * 8;
    const short* bp1 = bp0 + 16 * 256;
#pragma unroll
    for (int kc = 0; kc < 256; kc += 32) {
        bf16x8 a = *(const bf16x8*)(ap + kc);
        bf16x8 b0 = *(const bf16x8*)(bp0 + kc);
        bf16x8 b1 = *(const bf16x8*)(bp1 + kc);
        acc0 = mfma16(a, b0, acc0);
        acc1 = mfma16(a, b1, acc1);
    }
    float bi0 = bias[colBase + c], bi1 = bias[colBase + 16 + c];
#pragma unroll
    for (int r = 0; r < 4; r++) {
        int row = rowBase + 4 * g + r;
        float v0 = acc0[r] + bi0, v1 = acc1[r] + bi1;
        v0 = 0.5f * v0 * (1.f + erff(v0 * 0.7071067811865476f));
        v1 = 0.5f * v1 * (1.f + erff(v1 * 0.7071067811865476f));
        short* o = outb + (size_t)row * 256 + colBase;
        o[c] = f2bf(v0); o[16 + c] = f2bf(v1);
    }
}

// ------------------------------------------------ launch
extern "C" void kernel_launch(void* const* d_in, const int* in_sizes, int n_in,
                              void* d_out, int out_size, void* d_ws, size_t ws_size,
                              hipStream_t stream)
{
    const float* x_in   = (const float*)d_in[0];
    const float* qkv_w  = (const float*)d_in[1];
    const float* proj_w = (const float*)d_in[2];
    const float* proj_b = (const float*)d_in[3];
    const float* w1     = (const float*)d_in[4];
    const float* b1     = (const float*)d_in[5];
    const float* w2     = (const float*)d_in[6];
    const float* b2     = (const float*)d_in[7];
    const float* g1     = (const float*)d_in[8];
    const float* be1    = (const float*)d_in[9];
    const float* g2     = (const float*)d_in[10];
    const float* be2    = (const float*)d_in[11];
    float* outp = (float*)d_out;

    char* p = (char*)d_ws;
    float* xf   = (float*)p;  p += (size_t)Md * Cd * 4;
    short* xb   = (short*)p;  p += (size_t)Md * Cd * 2;
    short* Qb   = (short*)p;  p += (size_t)Md * Cd * 2;
    short* Kb   = (short*)p;  p += (size_t)Md * Cd * 2;
    short* Vtb  = (short*)p;  p += (size_t)Md * Cd * 2;
    short* attb = (short*)p;  p += (size_t)Md * Cd * 2;   // aliased: fc1 out
    short* fc1b = attb;
    float* OP   = (float*)p;  p += (size_t)SPLITd * U32d * 1024 * 4;
    float* Lsum = (float*)p;  p += (size_t)SPLITd * U32d * 32 * 4;
    short* qkvT = (short*)p;  p += (size_t)Ld * 768 * 256 * 2;
    short* projT= (short*)p;  p += (size_t)Ld * 256 * 256 * 2;
    short* w1T  = (short*)p;  p += (size_t)Ld * 256 * 256 * 2;
    short* w2T  = (short*)p;  p += (size_t)Ld * 256 * 256 * 2;

    const float QSCALE = 0.17677669529663687f * 1.4426950408889634f; // 1/sqrt(32)*log2e
    wtrans_kernel<<<dim3(24, 8, Ld), 256, 0, stream>>>(qkv_w, qkvT, 768, QSCALE, 256);
    wtrans_kernel<<<dim3(8, 8, Ld), 256, 0, stream>>>(proj_w, projT, 256, 1.f, 0);
    wtrans_kernel<<<dim3(8, 8, Ld), 256, 0, stream>>>(w1, w1T, 256, 1.f, 0);
    wtrans_kernel<<<dim3(8, 8, Ld), 256, 0, stream>>>(w2, w2T, 256, 1.f, 0);
    pos_add_kernel<<<Md * Cd / 256, 256, 0, stream>>>(x_in, xf, xb);

    for (int l = 0; l < Ld; l++) {
        qkv_gemm_kernel<<<dim3(24, 32), 256, 0, stream>>>(
            xb, qkvT + (size_t)l * 768 * 256, Qb, Kb, Vtb);
        attn_part_kernel<<<dim3(16, BHd, SPLITd), 256, 0, stream>>>(Qb, Kb, Vtb, OP, Lsum);
        attn_combine_kernel<<<U32d, 256, 0, stream>>>(OP, Lsum, attb);
        gemm_ln_kernel<0><<<Md / 16, 256, 0, stream>>>(
            attb, projT + (size_t)l * 65536, proj_b + l * 256, xf,
            g1 + l * 256, be1 + l * 256, xf, xb);
        gemm_gelu_kernel<<<dim3(8, 64), 256, 0, stream>>>(
            xb, w1T + (size_t)l * 65536, b1 + l * 256, fc1b);
        if (l == Ld - 1)
            gemm_ln_kernel<1><<<Md / 16, 256, 0, stream>>>(
                fc1b, w2T + (size_t)l * 65536, b2 + l * 256, xf,
                g2 + l * 256, be2 + l * 256, outp, nullptr);
        else
            gemm_ln_kernel<0><<<Md / 16, 256, 0, stream>>>(
                fc1b, w2T + (size_t)l * 65536, b2 + l * 256, xf,
                g2 + l * 256, be2 + l * 256, xf, xb);
    }
}

// Round 6
// 376.049 us; speedup vs baseline: 3.6979x; 1.0646x over previous
//
#include <hip/hip_runtime.h>
#include <math.h>

#define Bd 2
#define Nd 2048
#define Cd 256
#define Ld 4
#define Hd 8
#define Md (Bd*Nd)      // 4096
#define BHd 16
#define U32d 1024       // (B*H)*(N/32) units of 32 q-rows
#define SPLITd 4

typedef __attribute__((ext_vector_type(8))) short bf16x8;
typedef __attribute__((ext_vector_type(4))) float f32x4;
typedef __attribute__((ext_vector_type(16))) float f32x16;
typedef __attribute__((ext_vector_type(4))) short shortx4;

static __device__ inline f32x4 mfma16(bf16x8 a, bf16x8 b, f32x4 c) {
    return __builtin_amdgcn_mfma_f32_16x16x32_bf16(a, b, c, 0, 0, 0);
}
static __device__ inline f32x16 mfma32(bf16x8 a, bf16x8 b, f32x16 c) {
    return __builtin_amdgcn_mfma_f32_32x32x16_bf16(a, b, c, 0, 0, 0);
}
static __device__ inline short f2bf(float f) {
    union { float f; unsigned u; } v; v.f = f;
    unsigned r = (v.u + 0x7fff + ((v.u >> 16) & 1)) >> 16;
    return (short)r;
}
static __device__ inline unsigned pkbf(float a, float b) {
    unsigned r;
    asm("v_cvt_pk_bf16_f32 %0, %1, %2" : "=v"(r) : "v"(a), "v"(b));
    return r;
}

// ------------------------------------------------ weight transpose + bf16
__global__ __launch_bounds__(256)
void wtrans_kernel(const float* __restrict__ src, short* __restrict__ dst,
                   int Nc, float scale, int scaleLim)
{
    __shared__ float tile[32][33];
    int l = blockIdx.z;
    src += (size_t)l * 256 * Nc;
    dst += (size_t)l * Nc * 256;
    int c0 = blockIdx.x * 32, k0 = blockIdx.y * 32;
    int tx = threadIdx.x & 31, ty = threadIdx.x >> 5;
#pragma unroll
    for (int i = 0; i < 4; i++) {
        int k = ty + 8 * i;
        tile[k][tx] = src[(size_t)(k0 + k) * Nc + c0 + tx];
    }
    __syncthreads();
#pragma unroll
    for (int i = 0; i < 4; i++) {
        int cc = ty + 8 * i;
        int col = c0 + cc;
        float v = tile[tx][cc];
        if (col < scaleLim) v *= scale;
        dst[(size_t)col * 256 + k0 + tx] = f2bf(v);
    }
}

// ------------------------------------------------ pos embed (dual out)
__global__ __launch_bounds__(256)
void pos_add_kernel(const float* __restrict__ xin, float* __restrict__ xf,
                    short* __restrict__ xb)
{
    int i = blockIdx.x * 256 + threadIdx.x;
    int c = i & (Cd - 1);
    int n = (i >> 8) & (Nd - 1);
    const float kneg = -9.210340371976184f / 256.0f;
    float div = __expf((float)(c & ~1) * kneg);
    float ang = (float)n * div;
    float pe = (c & 1) ? cosf(ang) : sinf(ang);
    float v = xin[i] + pe;
    xf[i] = v;
    xb[i] = f2bf(v);
}

// ------------------------------------------------ QKV GEMM (bf16, no LDS)
__global__ __launch_bounds__(256)
void qkv_gemm_kernel(const short* __restrict__ Ab, const short* __restrict__ WT,
                     short* __restrict__ Qb, short* __restrict__ Kb,
                     short* __restrict__ Vtb)
{
    int t = threadIdx.x, w = t >> 6, l = t & 63, c = l & 15, g = l >> 4;
    int rowBase = blockIdx.y * 128 + w * 32;
    int colBase = blockIdx.x * 32;
    const f32x4 zero = {0.f, 0.f, 0.f, 0.f};
    f32x4 acc[2][2] = {{zero, zero}, {zero, zero}};
    const short* ap0 = Ab + (size_t)(rowBase + c) * 256 + g * 8;
    const short* ap1 = ap0 + 16 * 256;
    const short* bp0 = WT + (size_t)(colBase + c) * 256 + g * 8;
    const short* bp1 = bp0 + 16 * 256;
#pragma unroll
    for (int kc = 0; kc < 256; kc += 32) {
        bf16x8 a0 = *(const bf16x8*)(ap0 + kc);
        bf16x8 a1 = *(const bf16x8*)(ap1 + kc);
        bf16x8 b0 = *(const bf16x8*)(bp0 + kc);
        bf16x8 b1 = *(const bf16x8*)(bp1 + kc);
        acc[0][0] = mfma16(a0, b0, acc[0][0]);
        acc[0][1] = mfma16(a0, b1, acc[0][1]);
        acc[1][0] = mfma16(a1, b0, acc[1][0]);
        acc[1][1] = mfma16(a1, b1, acc[1][1]);
    }
    int region = colBase >> 8;              // 0=Q 1=K 2=V (uniform per block)
    if (region < 2) {
        short* dst = (region == 0) ? Qb : Kb;
        int cb = colBase - region * 256;
#pragma unroll
        for (int m = 0; m < 2; m++)
#pragma unroll
            for (int n = 0; n < 2; n++)
#pragma unroll
                for (int r = 0; r < 4; r++)
                    dst[(size_t)(rowBase + 16 * m + 4 * g + r) * 256 + cb + 16 * n + c]
                        = f2bf(acc[m][n][r]);
    } else {
        int b = rowBase >> 11;
        int ntok0 = (rowBase & (Nd - 1)) + 4 * g;
#pragma unroll
        for (int m = 0; m < 2; m++)
#pragma unroll
            for (int n = 0; n < 2; n++) {
                int chg = colBase - 512 + 16 * n + c;        // h*32+chl
                shortx4 pkv;
#pragma unroll
                for (int r = 0; r < 4; r++) pkv[r] = f2bf(acc[m][n][r]);
                *(shortx4*)&Vtb[(size_t)((b * Hd + (chg >> 5)) * 32 + (chg & 31)) * Nd
                                + ntok0 + 16 * m] = pkv;
            }
    }
}

// ------------------------------------------------ attention partial
// 32x32 MFMA, fixed-max softmax (exp2 direct), no LDS/barriers, 2-stage prefetch.
__global__ __launch_bounds__(256)
void attn_part_kernel(const short* __restrict__ Qb, const short* __restrict__ Kb,
                      const short* __restrict__ Vtb, float* __restrict__ OP,
                      float* __restrict__ Lsum)
{
    int t = threadIdx.x, w = t >> 6, l = t & 63;
    int l5 = l >> 5, q32 = l & 31;
    bool low = (l5 == 0);
    int qt = blockIdx.x * 4 + w;
    int bh = blockIdx.y, part = blockIdx.z;
    int b = bh >> 3, h = bh & 7;

    bf16x8 qf0, qf1;
    {
        const short* qp = Qb + ((size_t)(b * Nd + qt * 32 + q32)) * 256 + h * 32 + 8 * l5;
        qf0 = *(const bf16x8*)qp;
        qf1 = *(const bf16x8*)(qp + 16);
    }
    const short* kp = Kb + (size_t)b * Nd * 256 + h * 32 + 8 * l5;
    const short* vp = Vtb + (size_t)(bh * 32 + q32) * Nd + 8 * l5;

    f32x16 O;
#pragma unroll
    for (int i = 0; i < 16; i++) O[i] = 0.f;
    float lsum = 0.f;

    const int kstart = part * (Nd / SPLITd);
    const int kend = (part + 1) * (Nd / SPLITd);

    bf16x8 kf[2][2], vv[4];
#pragma unroll
    for (int sb = 0; sb < 2; sb++)
#pragma unroll
        for (int ks = 0; ks < 2; ks++)
            kf[sb][ks] = *(const bf16x8*)(kp + (size_t)(kstart + 32 * sb + q32) * 256 + 16 * ks);
#pragma unroll
    for (int kc = 0; kc < 4; kc++)
        vv[kc] = *(const bf16x8*)(vp + kstart + 16 * kc);

    for (int k0 = kstart; k0 < kend; k0 += 64) {
        // prefetch next tile (clamped; last iter redundantly reloads current)
        int kn = (k0 + 64 < kend) ? (k0 + 64) : k0;
        bf16x8 kfn[2][2], vvn[4];
#pragma unroll
        for (int sb = 0; sb < 2; sb++)
#pragma unroll
            for (int ks = 0; ks < 2; ks++)
                kfn[sb][ks] = *(const bf16x8*)(kp + (size_t)(kn + 32 * sb + q32) * 256 + 16 * ks);
#pragma unroll
        for (int kc = 0; kc < 4; kc++)
            vvn[kc] = *(const bf16x8*)(vp + kn + 16 * kc);

#pragma unroll
        for (int sb = 0; sb < 2; sb++) {
            f32x16 s;
#pragma unroll
            for (int i = 0; i < 16; i++) s[i] = 0.f;
            s = mfma32(kf[sb][0], qf0, s);
            s = mfma32(kf[sb][1], qf1, s);
            float ps = 0.f;
#pragma unroll
            for (int i = 0; i < 16; i++) { s[i] = exp2f(s[i]); ps += s[i]; }
            ps += __shfl_xor(ps, 32, 64);
            lsum += ps;
            unsigned wd[8];
#pragma unroll
            for (int i = 0; i < 8; i++) wd[i] = pkbf(s[2 * i], s[2 * i + 1]);
#pragma unroll
            for (int half = 0; half < 2; half++) {
                int b0 = 4 * half;
                unsigned sx0 = (unsigned)__shfl_xor((int)wd[b0], 32, 64);
                unsigned sx1 = (unsigned)__shfl_xor((int)wd[b0 + 1], 32, 64);
                unsigned sx2 = (unsigned)__shfl_xor((int)wd[b0 + 2], 32, 64);
                unsigned sx3 = (unsigned)__shfl_xor((int)wd[b0 + 3], 32, 64);
                union { unsigned u[4]; bf16x8 v; } pa;
                pa.u[0] = low ? wd[b0] : sx2;
                pa.u[1] = low ? wd[b0 + 1] : sx3;
                pa.u[2] = low ? sx0 : wd[b0 + 2];
                pa.u[3] = low ? sx1 : wd[b0 + 3];
                O = mfma32(pa.v, vv[2 * sb + half], O);
            }
        }
#pragma unroll
        for (int sb = 0; sb < 2; sb++)
#pragma unroll
            for (int ks = 0; ks < 2; ks++) kf[sb][ks] = kfn[sb][ks];
#pragma unroll
        for (int kc = 0; kc < 4; kc++) vv[kc] = vvn[kc];
    }

    int u = bh * 64 + qt;
    float* op = OP + ((size_t)part * U32d + u) * 1024;
#pragma unroll
    for (int i = 0; i < 16; i++) {
        int q = (i & 3) + 8 * (i >> 2) + 4 * l5;
        op[q * 32 + q32] = O[i];
    }
    if (low) Lsum[((size_t)part * U32d + u) * 32 + q32] = lsum;
}

// ------------------------------------------------ proj GEMM fused with
// split-K combine + bias + residual + LN1. 512 thr / 8 waves / 16 rows.
__global__ __launch_bounds__(512)
void proj_ln_kernel(const float* __restrict__ OP, const float* __restrict__ Lsum,
                    const short* __restrict__ WT, const float* __restrict__ bias,
                    const float* __restrict__ resid, const float* __restrict__ gg,
                    const float* __restrict__ be, float* __restrict__ outf,
                    short* __restrict__ outb)
{
    __shared__ short Atile[16 * 264];
    __shared__ float red[8][16][2];
    int t = threadIdx.x;
    int rowBase = blockIdx.x * 16;

    // ---- combine: A[16][256] bf16 from OP/Lsum
    {
        int r = t >> 5, seg = t & 31;
        int grow = rowBase + r;
        int bb = grow >> 11;
        int qt = (grow & (Nd - 1)) >> 5;
        int q = grow & 31;
        int h = seg >> 2;
        int dh0 = (seg & 3) * 8;
        int u = (bb * Hd + h) * 64 + qt;
        float o[8] = {0.f, 0.f, 0.f, 0.f, 0.f, 0.f, 0.f, 0.f};
        float L = 0.f;
#pragma unroll
        for (int p = 0; p < SPLITd; p++) {
            const float* src = OP + ((size_t)p * U32d + u) * 1024 + q * 32 + dh0;
            float4 v0 = *(const float4*)src;
            float4 v1 = *(const float4*)(src + 4);
            o[0] += v0.x; o[1] += v0.y; o[2] += v0.z; o[3] += v0.w;
            o[4] += v1.x; o[5] += v1.y; o[6] += v1.z; o[7] += v1.w;
            L += Lsum[((size_t)p * U32d + u) * 32 + q];
        }
        float inv = 1.f / L;
        bf16x8 pk;
#pragma unroll
        for (int j = 0; j < 8; j++) pk[j] = f2bf(o[j] * inv);
        *(bf16x8*)&Atile[r * 264 + seg * 8] = pk;
    }
    __syncthreads();

    // ---- GEMM: wave w -> cols w*32 .. w*32+31
    int w = t >> 6, l = t & 63, c = l & 15, g = l >> 4;
    const f32x4 zero = {0.f, 0.f, 0.f, 0.f};
    f32x4 acc0 = zero, acc1 = zero;
    const short* bp0 = WT + (size_t)(w * 32 + c) * 256 + g * 8;
    const short* bp1 = bp0 + 16 * 256;
#pragma unroll
    for (int kc = 0; kc < 256; kc += 32) {
        bf16x8 a = *(const bf16x8*)&Atile[c * 264 + g * 8 + kc];
        acc0 = mfma16(a, *(const bf16x8*)(bp0 + kc), acc0);
        acc1 = mfma16(a, *(const bf16x8*)(bp1 + kc), acc1);
    }

    // ---- bias + residual, LN stats
    float vv[2][4], s_[4] = {0.f, 0.f, 0.f, 0.f}, sq_[4] = {0.f, 0.f, 0.f, 0.f};
    int col0 = w * 32 + c, col1 = col0 + 16;
    float bi0 = bias[col0], bi1 = bias[col1];
#pragma unroll
    for (int r = 0; r < 4; r++) {
        int row = rowBase + 4 * g + r;
        float v0 = acc0[r] + bi0 + resid[(size_t)row * 256 + col0];
        float v1 = acc1[r] + bi1 + resid[(size_t)row * 256 + col1];
        vv[0][r] = v0; vv[1][r] = v1;
        s_[r] += v0 + v1; sq_[r] += v0 * v0 + v1 * v1;
    }
#pragma unroll
    for (int off = 1; off <= 8; off <<= 1)
#pragma unroll
        for (int r = 0; r < 4; r++) {
            s_[r] += __shfl_xor(s_[r], off, 64);
            sq_[r] += __shfl_xor(sq_[r], off, 64);
        }
    if (c == 0)
#pragma unroll
        for (int r = 0; r < 4; r++) {
            red[w][4 * g + r][0] = s_[r];
            red[w][4 * g + r][1] = sq_[r];
        }
    __syncthreads();
    float mu[4], rs[4];
#pragma unroll
    for (int r = 0; r < 4; r++) {
        float S = 0.f, Q = 0.f;
#pragma unroll
        for (int ww = 0; ww < 8; ww++) { S += red[ww][4 * g + r][0]; Q += red[ww][4 * g + r][1]; }
        mu[r] = S * (1.f / 256.f);
        rs[r] = rsqrtf(Q * (1.f / 256.f) - mu[r] * mu[r] + 1e-6f);
    }
    float gv0 = gg[col0], bv0 = be[col0], gv1 = gg[col1], bv1 = be[col1];
#pragma unroll
    for (int r = 0; r < 4; r++) {
        int row = rowBase + 4 * g + r;
        float o0 = (vv[0][r] - mu[r]) * rs[r] * gv0 + bv0;
        float o1 = (vv[1][r] - mu[r]) * rs[r] * gv1 + bv1;
        outf[(size_t)row * 256 + col0] = o0;
        outf[(size_t)row * 256 + col1] = o1;
        outb[(size_t)row * 256 + col0] = f2bf(o0);
        outb[(size_t)row * 256 + col1] = f2bf(o1);
    }
}

// ------------------------------------------------ fused MLP:
// fc1+bias+GELU -> LDS -> fc2+bias + residual + LN2. 512 thr / 8 waves / 16 rows.
template<int LAST>
__global__ __launch_bounds__(512)
void mlp_kernel(const short* __restrict__ xbin, const short* __restrict__ W1T,
                const float* __restrict__ b1, const short* __restrict__ W2T,
                const float* __restrict__ b2, const float* __restrict__ resid,
                const float* __restrict__ gg, const float* __restrict__ be,
                float* __restrict__ outf, short* __restrict__ outb)
{
    __shared__ short A1[16 * 264];
    __shared__ short A2[16 * 264];
    __shared__ float red[8][16][2];
    int t = threadIdx.x;
    int rowBase = blockIdx.x * 16;

    // stage A1 from xb
    {
        int r = t >> 5, seg = t & 31;
        *(bf16x8*)&A1[r * 264 + seg * 8] =
            *(const bf16x8*)(xbin + (size_t)(rowBase + r) * 256 + seg * 8);
    }
    __syncthreads();

    int w = t >> 6, l = t & 63, c = l & 15, g = l >> 4;
    const f32x4 zero = {0.f, 0.f, 0.f, 0.f};
    int col0 = w * 32 + c, col1 = col0 + 16;

    // ---- fc1 + GELU -> A2
    {
        f32x4 acc0 = zero, acc1 = zero;
        const short* bp0 = W1T + (size_t)(w * 32 + c) * 256 + g * 8;
        const short* bp1 = bp0 + 16 * 256;
#pragma unroll
        for (int kc = 0; kc < 256; kc += 32) {
            bf16x8 a = *(const bf16x8*)&A1[c * 264 + g * 8 + kc];
            acc0 = mfma16(a, *(const bf16x8*)(bp0 + kc), acc0);
            acc1 = mfma16(a, *(const bf16x8*)(bp1 + kc), acc1);
        }
        float bi0 = b1[col0], bi1 = b1[col1];
#pragma unroll
        for (int r = 0; r < 4; r++) {
            float v0 = acc0[r] + bi0, v1 = acc1[r] + bi1;
            v0 = 0.5f * v0 * (1.f + erff(v0 * 0.7071067811865476f));
            v1 = 0.5f * v1 * (1.f + erff(v1 * 0.7071067811865476f));
            A2[(4 * g + r) * 264 + col0] = f2bf(v0);
            A2[(4 * g + r) * 264 + col1] = f2bf(v1);
        }
    }
    __syncthreads();

    // ---- fc2 + bias + residual + LN2
    f32x4 acc0 = zero, acc1 = zero;
    const short* bp0 = W2T + (size_t)(w * 32 + c) * 256 + g * 8;
    const short* bp1 = bp0 + 16 * 256;
#pragma unroll
    for (int kc = 0; kc < 256; kc += 32) {
        bf16x8 a = *(const bf16x8*)&A2[c * 264 + g * 8 + kc];
        acc0 = mfma16(a, *(const bf16x8*)(bp0 + kc), acc0);
        acc1 = mfma16(a, *(const bf16x8*)(bp1 + kc), acc1);
    }
    float vv[2][4], s_[4] = {0.f, 0.f, 0.f, 0.f}, sq_[4] = {0.f, 0.f, 0.f, 0.f};
    float bi0 = b2[col0], bi1 = b2[col1];
#pragma unroll
    for (int r = 0; r < 4; r++) {
        int row = rowBase + 4 * g + r;
        float v0 = acc0[r] + bi0 + resid[(size_t)row * 256 + col0];
        float v1 = acc1[r] + bi1 + resid[(size_t)row * 256 + col1];
        vv[0][r] = v0; vv[1][r] = v1;
        s_[r] += v0 + v1; sq_[r] += v0 * v0 + v1 * v1;
    }
#pragma unroll
    for (int off = 1; off <= 8; off <<= 1)
#pragma unroll
        for (int r = 0; r < 4; r++) {
            s_[r] += __shfl_xor(s_[r], off, 64);
            sq_[r] += __shfl_xor(sq_[r], off, 64);
        }
    if (c == 0)
#pragma unroll
        for (int r = 0; r < 4; r++) {
            red[w][4 * g + r][0] = s_[r];
            red[w][4 * g + r][1] = sq_[r];
        }
    __syncthreads();
    float mu[4], rs[4];
#pragma unroll
    for (int r = 0; r < 4; r++) {
        float S = 0.f, Q = 0.f;
#pragma unroll
        for (int ww = 0; ww < 8; ww++) { S += red[ww][4 * g + r][0]; Q += red[ww][4 * g + r][1]; }
        mu[r] = S * (1.f / 256.f);
        rs[r] = rsqrtf(Q * (1.f / 256.f) - mu[r] * mu[r] + 1e-6f);
    }
    float gv0 = gg[col0], bv0 = be[col0], gv1 = gg[col1], bv1 = be[col1];
#pragma unroll
    for (int r = 0; r < 4; r++) {
        int row = rowBase + 4 * g + r;
        float o0 = (vv[0][r] - mu[r]) * rs[r] * gv0 + bv0;
        float o1 = (vv[1][r] - mu[r]) * rs[r] * gv1 + bv1;
        outf[(size_t)row * 256 + col0] = o0;
        outf[(size_t)row * 256 + col1] = o1;
        if (!LAST) {
            outb[(size_t)row * 256 + col0] = f2bf(o0);
            outb[(size_t)row * 256 + col1] = f2bf(o1);
        }
    }
}

// ------------------------------------------------ launch
extern "C" void kernel_launch(void* const* d_in, const int* in_sizes, int n_in,
                              void* d_out, int out_size, void* d_ws, size_t ws_size,
                              hipStream_t stream)
{
    const float* x_in   = (const float*)d_in[0];
    const float* qkv_w  = (const float*)d_in[1];
    const float* proj_w = (const float*)d_in[2];
    const float* proj_b = (const float*)d_in[3];
    const float* w1     = (const float*)d_in[4];
    const float* b1     = (const float*)d_in[5];
    const float* w2     = (const float*)d_in[6];
    const float* b2     = (const float*)d_in[7];
    const float* g1     = (const float*)d_in[8];
    const float* be1    = (const float*)d_in[9];
    const float* g2     = (const float*)d_in[10];
    const float* be2    = (const float*)d_in[11];
    float* outp = (float*)d_out;

    char* p = (char*)d_ws;
    float* xf   = (float*)p;  p += (size_t)Md * Cd * 4;
    short* xb   = (short*)p;  p += (size_t)Md * Cd * 2;
    short* Qb   = (short*)p;  p += (size_t)Md * Cd * 2;
    short* Kb   = (short*)p;  p += (size_t)Md * Cd * 2;
    short* Vtb  = (short*)p;  p += (size_t)Md * Cd * 2;
    float* OP   = (float*)p;  p += (size_t)SPLITd * U32d * 1024 * 4;
    float* Lsum = (float*)p;  p += (size_t)SPLITd * U32d * 32 * 4;
    short* qkvT = (short*)p;  p += (size_t)Ld * 768 * 256 * 2;
    short* projT= (short*)p;  p += (size_t)Ld * 256 * 256 * 2;
    short* w1T  = (short*)p;  p += (size_t)Ld * 256 * 256 * 2;
    short* w2T  = (short*)p;  p += (size_t)Ld * 256 * 256 * 2;

    const float QSCALE = 0.17677669529663687f * 1.4426950408889634f; // 1/sqrt(32)*log2e
    wtrans_kernel<<<dim3(24, 8, Ld), 256, 0, stream>>>(qkv_w, qkvT, 768, QSCALE, 256);
    wtrans_kernel<<<dim3(8, 8, Ld), 256, 0, stream>>>(proj_w, projT, 256, 1.f, 0);
    wtrans_kernel<<<dim3(8, 8, Ld), 256, 0, stream>>>(w1, w1T, 256, 1.f, 0);
    wtrans_kernel<<<dim3(8, 8, Ld), 256, 0, stream>>>(w2, w2T, 256, 1.f, 0);
    pos_add_kernel<<<Md * Cd / 256, 256, 0, stream>>>(x_in, xf, xb);

    for (int l = 0; l < Ld; l++) {
        qkv_gemm_kernel<<<dim3(24, 32), 256, 0, stream>>>(
            xb, qkvT + (size_t)l * 768 * 256, Qb, Kb, Vtb);
        attn_part_kernel<<<dim3(16, BHd, SPLITd), 256, 0, stream>>>(Qb, Kb, Vtb, OP, Lsum);
        proj_ln_kernel<<<Md / 16, 512, 0, stream>>>(
            OP, Lsum, projT + (size_t)l * 65536, proj_b + l * 256, xf,
            g1 + l * 256, be1 + l * 256, xf, xb);
        if (l == Ld - 1)
            mlp_kernel<1><<<Md / 16, 512, 0, stream>>>(
                xb, w1T + (size_t)l * 65536, b1 + l * 256,
                w2T + (size_t)l * 65536, b2 + l * 256, xf,
                g2 + l * 256, be2 + l * 256, outp, nullptr);
        else
            mlp_kernel<0><<<Md / 16, 512, 0, stream>>>(
                xb, w1T + (size_t)l * 65536, b1 + l * 256,
                w2T + (size_t)l * 65536, b2 + l * 256, xf,
                g2 + l * 256, be2 + l * 256, xf, xb);
    }
}

// Round 7
// 374.495 us; speedup vs baseline: 3.7132x; 1.0042x over previous
//
#include <hip/hip_runtime.h>
#include <math.h>

#define Bd 2
#define Nd 2048
#define Cd 256
#define Ld 4
#define Hd 8
#define Md (Bd*Nd)      // 4096
#define BHd 16
#define U32d 1024       // (B*H)*(N/32) units of 32 q-rows
#define SPLITd 4

typedef __attribute__((ext_vector_type(8))) short bf16x8;
typedef __attribute__((ext_vector_type(4))) float f32x4;
typedef __attribute__((ext_vector_type(16))) float f32x16;
typedef __attribute__((ext_vector_type(4))) short shortx4;

static __device__ inline f32x4 mfma16(bf16x8 a, bf16x8 b, f32x4 c) {
    return __builtin_amdgcn_mfma_f32_16x16x32_bf16(a, b, c, 0, 0, 0);
}
static __device__ inline f32x16 mfma32(bf16x8 a, bf16x8 b, f32x16 c) {
    return __builtin_amdgcn_mfma_f32_32x32x16_bf16(a, b, c, 0, 0, 0);
}
static __device__ inline short f2bf(float f) {
    union { float f; unsigned u; } v; v.f = f;
    unsigned r = (v.u + 0x7fff + ((v.u >> 16) & 1)) >> 16;
    return (short)r;
}
static __device__ inline unsigned pkbf(float a, float b) {
    unsigned r;
    asm("v_cvt_pk_bf16_f32 %0, %1, %2" : "=v"(r) : "v"(a), "v"(b));
    return r;
}
static __device__ inline float bf2f(unsigned u) {
    return __uint_as_float((u & 0xffffu) << 16);
}

// ------------------------------------------------ fused prep:
// blocks [0,1536): weight transposes; [1536, 1536+4096): pos-embed add
__global__ __launch_bounds__(256)
void prep_kernel(const float* __restrict__ x_in, const float* __restrict__ qkv_w,
                 const float* __restrict__ proj_w, const float* __restrict__ w1,
                 const float* __restrict__ w2, float* __restrict__ xf,
                 short* __restrict__ xb, short* __restrict__ qkvT,
                 short* __restrict__ projT, short* __restrict__ w1T,
                 short* __restrict__ w2T, float qscale)
{
    __shared__ float tile[32][33];
    int id = blockIdx.x;
    if (id < 1536) {
        const float* src; short* dst; int Nc; float scale; int lim; int rem; int l;
        if (id < 768)       { l = id / 192;         rem = id % 192; src = qkv_w;  dst = qkvT;  Nc = 768; scale = qscale; lim = 256; }
        else if (id < 1024) { l = (id - 768) / 64;  rem = (id - 768) % 64;  src = proj_w; dst = projT; Nc = 256; scale = 1.f; lim = 0; }
        else if (id < 1280) { l = (id - 1024) / 64; rem = (id - 1024) % 64; src = w1;     dst = w1T;   Nc = 256; scale = 1.f; lim = 0; }
        else                { l = (id - 1280) / 64; rem = (id - 1280) % 64; src = w2;     dst = w2T;   Nc = 256; scale = 1.f; lim = 0; }
        int nb = Nc >> 5;
        int c0 = (rem % nb) * 32, k0 = (rem / nb) * 32;
        src += (size_t)l * 256 * Nc;
        dst += (size_t)l * Nc * 256;
        int tx = threadIdx.x & 31, ty = threadIdx.x >> 5;
#pragma unroll
        for (int i = 0; i < 4; i++) {
            int k = ty + 8 * i;
            tile[k][tx] = src[(size_t)(k0 + k) * Nc + c0 + tx];
        }
        __syncthreads();
#pragma unroll
        for (int i = 0; i < 4; i++) {
            int cc = ty + 8 * i;
            int col = c0 + cc;
            float v = tile[tx][cc];
            if (col < lim) v *= scale;
            dst[(size_t)col * 256 + k0 + tx] = f2bf(v);
        }
    } else {
        int i = (id - 1536) * 256 + threadIdx.x;
        int c = i & (Cd - 1);
        int n = (i >> 8) & (Nd - 1);
        const float kneg = -9.210340371976184f / 256.0f;
        float div = __expf((float)(c & ~1) * kneg);
        float ang = (float)n * div;
        float pe = (c & 1) ? cosf(ang) : sinf(ang);
        float v = x_in[i] + pe;
        xf[i] = v;
        xb[i] = f2bf(v);
    }
}

// ------------------------------------------------ QKV GEMM (bf16, no LDS)
__global__ __launch_bounds__(256)
void qkv_gemm_kernel(const short* __restrict__ Ab, const short* __restrict__ WT,
                     short* __restrict__ Qb, short* __restrict__ Kb,
                     short* __restrict__ Vtb)
{
    int t = threadIdx.x, w = t >> 6, l = t & 63, c = l & 15, g = l >> 4;
    int rowBase = blockIdx.y * 128 + w * 32;
    int colBase = blockIdx.x * 32;
    const f32x4 zero = {0.f, 0.f, 0.f, 0.f};
    f32x4 acc[2][2] = {{zero, zero}, {zero, zero}};
    const short* ap0 = Ab + (size_t)(rowBase + c) * 256 + g * 8;
    const short* ap1 = ap0 + 16 * 256;
    const short* bp0 = WT + (size_t)(colBase + c) * 256 + g * 8;
    const short* bp1 = bp0 + 16 * 256;
#pragma unroll
    for (int kc = 0; kc < 256; kc += 32) {
        bf16x8 a0 = *(const bf16x8*)(ap0 + kc);
        bf16x8 a1 = *(const bf16x8*)(ap1 + kc);
        bf16x8 b0 = *(const bf16x8*)(bp0 + kc);
        bf16x8 b1 = *(const bf16x8*)(bp1 + kc);
        acc[0][0] = mfma16(a0, b0, acc[0][0]);
        acc[0][1] = mfma16(a0, b1, acc[0][1]);
        acc[1][0] = mfma16(a1, b0, acc[1][0]);
        acc[1][1] = mfma16(a1, b1, acc[1][1]);
    }
    int region = colBase >> 8;              // 0=Q 1=K 2=V (uniform per block)
    if (region < 2) {
        short* dst = (region == 0) ? Qb : Kb;
        int cb = colBase - region * 256;
#pragma unroll
        for (int m = 0; m < 2; m++)
#pragma unroll
            for (int n = 0; n < 2; n++)
#pragma unroll
                for (int r = 0; r < 4; r++)
                    dst[(size_t)(rowBase + 16 * m + 4 * g + r) * 256 + cb + 16 * n + c]
                        = f2bf(acc[m][n][r]);
    } else {
        int b = rowBase >> 11;
        int ntok0 = (rowBase & (Nd - 1)) + 4 * g;
#pragma unroll
        for (int m = 0; m < 2; m++)
#pragma unroll
            for (int n = 0; n < 2; n++) {
                int chg = colBase - 512 + 16 * n + c;        // h*32+chl
                shortx4 pkv;
#pragma unroll
                for (int r = 0; r < 4; r++) pkv[r] = f2bf(acc[m][n][r]);
                *(shortx4*)&Vtb[(size_t)((b * Hd + (chg >> 5)) * 32 + (chg & 31)) * Nd
                                + ntok0 + 16 * m] = pkv;
            }
    }
}

// ------------------------------------------------ attention partial
// 32x32 MFMA, fixed-max softmax (exp2 direct), permlane32 relayout,
// bf16-packed partials, register prefetch. No LDS, no barriers.
__global__ __launch_bounds__(256)
void attn_part_kernel(const short* __restrict__ Qb, const short* __restrict__ Kb,
                      const short* __restrict__ Vtb, unsigned* __restrict__ OPb,
                      float* __restrict__ Lsum)
{
    int t = threadIdx.x, w = t >> 6, l = t & 63;
    int l5 = l >> 5, q32 = l & 31;
    int qt = blockIdx.x * 4 + w;
    int bh = blockIdx.y, part = blockIdx.z;
    int b = bh >> 3, h = bh & 7;

    bf16x8 qf0, qf1;
    {
        const short* qp = Qb + ((size_t)(b * Nd + qt * 32 + q32)) * 256 + h * 32 + 8 * l5;
        qf0 = *(const bf16x8*)qp;
        qf1 = *(const bf16x8*)(qp + 16);
    }
    const short* kp = Kb + (size_t)b * Nd * 256 + h * 32 + 8 * l5;
    const short* vp = Vtb + (size_t)(bh * 32 + q32) * Nd + 8 * l5;

    f32x16 O;
#pragma unroll
    for (int i = 0; i < 16; i++) O[i] = 0.f;
    float lsum = 0.f;

    const int kstart = part * (Nd / SPLITd);
    const int kend = (part + 1) * (Nd / SPLITd);

    bf16x8 kf[2][2], vv[4];
#pragma unroll
    for (int sb = 0; sb < 2; sb++)
#pragma unroll
        for (int ks = 0; ks < 2; ks++)
            kf[sb][ks] = *(const bf16x8*)(kp + (size_t)(kstart + 32 * sb + q32) * 256 + 16 * ks);
#pragma unroll
    for (int kc = 0; kc < 4; kc++)
        vv[kc] = *(const bf16x8*)(vp + kstart + 16 * kc);

    for (int k0 = kstart; k0 < kend; k0 += 64) {
        bool has_next = (k0 + 64) < kend;
        bf16x8 kfn[2][2], vvn[4];
        if (has_next) {
            int kn = k0 + 64;
#pragma unroll
            for (int sb = 0; sb < 2; sb++)
#pragma unroll
                for (int ks = 0; ks < 2; ks++)
                    kfn[sb][ks] = *(const bf16x8*)(kp + (size_t)(kn + 32 * sb + q32) * 256 + 16 * ks);
#pragma unroll
            for (int kc = 0; kc < 4; kc++)
                vvn[kc] = *(const bf16x8*)(vp + kn + 16 * kc);
        }

#pragma unroll
        for (int sb = 0; sb < 2; sb++) {
            f32x16 s;
#pragma unroll
            for (int i = 0; i < 16; i++) s[i] = 0.f;
            s = mfma32(kf[sb][0], qf0, s);
            s = mfma32(kf[sb][1], qf1, s);
            float ps = 0.f;
#pragma unroll
            for (int i = 0; i < 16; i++) { s[i] = exp2f(s[i]); ps += s[i]; }
            lsum += ps;                       // cross-half combine deferred
            unsigned wd[8];
#pragma unroll
            for (int i = 0; i < 8; i++) wd[i] = pkbf(s[2 * i], s[2 * i + 1]);
#pragma unroll
            for (int half = 0; half < 2; half++) {
                unsigned a0 = wd[4 * half], a1 = wd[4 * half + 1];
                unsigned b0 = wd[4 * half + 2], b1 = wd[4 * half + 3];
                asm("v_permlane32_swap_b32 %0, %1" : "+v"(a0), "+v"(b0));
                asm("v_permlane32_swap_b32 %0, %1" : "+v"(a1), "+v"(b1));
                union { unsigned u[4]; bf16x8 v; } pa;
                pa.u[0] = a0; pa.u[1] = a1; pa.u[2] = b0; pa.u[3] = b1;
                O = mfma32(pa.v, vv[2 * sb + half], O);
            }
        }
        if (has_next) {
#pragma unroll
            for (int sb = 0; sb < 2; sb++)
#pragma unroll
                for (int ks = 0; ks < 2; ks++) kf[sb][ks] = kfn[sb][ks];
#pragma unroll
            for (int kc = 0; kc < 4; kc++) vv[kc] = vvn[kc];
        }
    }

    lsum += __shfl_xor(lsum, 32, 64);

    int u = bh * 64 + qt;
    unsigned* opb = OPb + ((size_t)part * U32d + u) * 512;
#pragma unroll
    for (int i = 0; i < 16; i += 2) {
        int q = (i & 3) + 8 * (i >> 2) + 4 * l5;     // even row of the pair
        opb[(q >> 1) * 32 + q32] = pkbf(O[i], O[i + 1]);
    }
    if (l5 == 0) Lsum[((size_t)part * U32d + u) * 32 + q32] = lsum;
}

// ------------------------------------------------ proj GEMM fused with
// split-K combine + bias + residual + LN1. 512 thr / 8 waves / 16 rows.
__global__ __launch_bounds__(512)
void proj_ln_kernel(const unsigned* __restrict__ OPb, const float* __restrict__ Lsum,
                    const short* __restrict__ WT, const float* __restrict__ bias,
                    const float* __restrict__ resid, const float* __restrict__ gg,
                    const float* __restrict__ be, float* __restrict__ outf,
                    short* __restrict__ outb)
{
    __shared__ short Atile[16 * 264];
    __shared__ float red[8][16][2];
    int t = threadIdx.x;
    int rowBase = blockIdx.x * 16;

    // ---- combine: A[16][256] bf16 from OPb/Lsum
    {
        int r = t >> 5, seg = t & 31;
        int grow = rowBase + r;
        int bb = grow >> 11;
        int qt = (grow & (Nd - 1)) >> 5;
        int q = grow & 31;
        int h = seg >> 2;
        int dh0 = (seg & 3) * 8;
        int u = (bb * Hd + h) * 64 + qt;
        int sh = (q & 1) * 16;
        float o[8] = {0.f, 0.f, 0.f, 0.f, 0.f, 0.f, 0.f, 0.f};
        float L = 0.f;
#pragma unroll
        for (int p = 0; p < SPLITd; p++) {
            const unsigned* src = OPb + ((size_t)p * U32d + u) * 512 + (q >> 1) * 32 + dh0;
            uint4 w0 = *(const uint4*)src;
            uint4 w1 = *(const uint4*)(src + 4);
            o[0] += bf2f(w0.x >> sh); o[1] += bf2f(w0.y >> sh);
            o[2] += bf2f(w0.z >> sh); o[3] += bf2f(w0.w >> sh);
            o[4] += bf2f(w1.x >> sh); o[5] += bf2f(w1.y >> sh);
            o[6] += bf2f(w1.z >> sh); o[7] += bf2f(w1.w >> sh);
            L += Lsum[((size_t)p * U32d + u) * 32 + q];
        }
        float inv = 1.f / L;
        bf16x8 pk;
#pragma unroll
        for (int j = 0; j < 8; j++) pk[j] = f2bf(o[j] * inv);
        *(bf16x8*)&Atile[r * 264 + seg * 8] = pk;
    }
    __syncthreads();

    // ---- GEMM: wave w -> cols w*32 .. w*32+31
    int w = t >> 6, l = t & 63, c = l & 15, g = l >> 4;
    const f32x4 zero = {0.f, 0.f, 0.f, 0.f};
    f32x4 acc0 = zero, acc1 = zero;
    const short* bp0 = WT + (size_t)(w * 32 + c) * 256 + g * 8;
    const short* bp1 = bp0 + 16 * 256;
#pragma unroll
    for (int kc = 0; kc < 256; kc += 32) {
        bf16x8 a = *(const bf16x8*)&Atile[c * 264 + g * 8 + kc];
        acc0 = mfma16(a, *(const bf16x8*)(bp0 + kc), acc0);
        acc1 = mfma16(a, *(const bf16x8*)(bp1 + kc), acc1);
    }

    // ---- bias + residual, LN stats
    float vv[2][4], s_[4] = {0.f, 0.f, 0.f, 0.f}, sq_[4] = {0.f, 0.f, 0.f, 0.f};
    int col0 = w * 32 + c, col1 = col0 + 16;
    float bi0 = bias[col0], bi1 = bias[col1];
#pragma unroll
    for (int r = 0; r < 4; r++) {
        int row = rowBase + 4 * g + r;
        float v0 = acc0[r] + bi0 + resid[(size_t)row * 256 + col0];
        float v1 = acc1[r] + bi1 + resid[(size_t)row * 256 + col1];
        vv[0][r] = v0; vv[1][r] = v1;
        s_[r] += v0 + v1; sq_[r] += v0 * v0 + v1 * v1;
    }
#pragma unroll
    for (int off = 1; off <= 8; off <<= 1)
#pragma unroll
        for (int r = 0; r < 4; r++) {
            s_[r] += __shfl_xor(s_[r], off, 64);
            sq_[r] += __shfl_xor(sq_[r], off, 64);
        }
    if (c == 0)
#pragma unroll
        for (int r = 0; r < 4; r++) {
            red[w][4 * g + r][0] = s_[r];
            red[w][4 * g + r][1] = sq_[r];
        }
    __syncthreads();
    float mu[4], rs[4];
#pragma unroll
    for (int r = 0; r < 4; r++) {
        float S = 0.f, Q = 0.f;
#pragma unroll
        for (int ww = 0; ww < 8; ww++) { S += red[ww][4 * g + r][0]; Q += red[ww][4 * g + r][1]; }
        mu[r] = S * (1.f / 256.f);
        rs[r] = rsqrtf(Q * (1.f / 256.f) - mu[r] * mu[r] + 1e-6f);
    }
    float gv0 = gg[col0], bv0 = be[col0], gv1 = gg[col1], bv1 = be[col1];
#pragma unroll
    for (int r = 0; r < 4; r++) {
        int row = rowBase + 4 * g + r;
        float o0 = (vv[0][r] - mu[r]) * rs[r] * gv0 + bv0;
        float o1 = (vv[1][r] - mu[r]) * rs[r] * gv1 + bv1;
        outf[(size_t)row * 256 + col0] = o0;
        outf[(size_t)row * 256 + col1] = o1;
        outb[(size_t)row * 256 + col0] = f2bf(o0);
        outb[(size_t)row * 256 + col1] = f2bf(o1);
    }
}

// ------------------------------------------------ fused MLP:
// fc1+bias+GELU -> LDS -> fc2+bias + residual + LN2. 512 thr / 8 waves / 16 rows.
template<int LAST>
__global__ __launch_bounds__(512)
void mlp_kernel(const short* __restrict__ xbin, const short* __restrict__ W1T,
                const float* __restrict__ b1, const short* __restrict__ W2T,
                const float* __restrict__ b2, const float* __restrict__ resid,
                const float* __restrict__ gg, const float* __restrict__ be,
                float* __restrict__ outf, short* __restrict__ outb)
{
    __shared__ short A1[16 * 264];
    __shared__ short A2[16 * 264];
    __shared__ float red[8][16][2];
    int t = threadIdx.x;
    int rowBase = blockIdx.x * 16;

    {
        int r = t >> 5, seg = t & 31;
        *(bf16x8*)&A1[r * 264 + seg * 8] =
            *(const bf16x8*)(xbin + (size_t)(rowBase + r) * 256 + seg * 8);
    }
    __syncthreads();

    int w = t >> 6, l = t & 63, c = l & 15, g = l >> 4;
    const f32x4 zero = {0.f, 0.f, 0.f, 0.f};
    int col0 = w * 32 + c, col1 = col0 + 16;

    // ---- fc1 + GELU -> A2
    {
        f32x4 acc0 = zero, acc1 = zero;
        const short* bp0 = W1T + (size_t)(w * 32 + c) * 256 + g * 8;
        const short* bp1 = bp0 + 16 * 256;
#pragma unroll
        for (int kc = 0; kc < 256; kc += 32) {
            bf16x8 a = *(const bf16x8*)&A1[c * 264 + g * 8 + kc];
            acc0 = mfma16(a, *(const bf16x8*)(bp0 + kc), acc0);
            acc1 = mfma16(a, *(const bf16x8*)(bp1 + kc), acc1);
        }
        float bi0 = b1[col0], bi1 = b1[col1];
#pragma unroll
        for (int r = 0; r < 4; r++) {
            float v0 = acc0[r] + bi0, v1 = acc1[r] + bi1;
            v0 = 0.5f * v0 * (1.f + erff(v0 * 0.7071067811865476f));
            v1 = 0.5f * v1 * (1.f + erff(v1 * 0.7071067811865476f));
            A2[(4 * g + r) * 264 + col0] = f2bf(v0);
            A2[(4 * g + r) * 264 + col1] = f2bf(v1);
        }
    }
    __syncthreads();

    // ---- fc2 + bias + residual + LN2
    f32x4 acc0 = zero, acc1 = zero;
    const short* bp0 = W2T + (size_t)(w * 32 + c) * 256 + g * 8;
    const short* bp1 = bp0 + 16 * 256;
#pragma unroll
    for (int kc = 0; kc < 256; kc += 32) {
        bf16x8 a = *(const bf16x8*)&A2[c * 264 + g * 8 + kc];
        acc0 = mfma16(a, *(const bf16x8*)(bp0 + kc), acc0);
        acc1 = mfma16(a, *(const bf16x8*)(bp1 + kc), acc1);
    }
    float vv[2][4], s_[4] = {0.f, 0.f, 0.f, 0.f}, sq_[4] = {0.f, 0.f, 0.f, 0.f};
    float bi0 = b2[col0], bi1 = b2[col1];
#pragma unroll
    for (int r = 0; r < 4; r++) {
        int row = rowBase + 4 * g + r;
        float v0 = acc0[r] + bi0 + resid[(size_t)row * 256 + col0];
        float v1 = acc1[r] + bi1 + resid[(size_t)row * 256 + col1];
        vv[0][r] = v0; vv[1][r] = v1;
        s_[r] += v0 + v1; sq_[r] += v0 * v0 + v1 * v1;
    }
#pragma unroll
    for (int off = 1; off <= 8; off <<= 1)
#pragma unroll
        for (int r = 0; r < 4; r++) {
            s_[r] += __shfl_xor(s_[r], off, 64);
            sq_[r] += __shfl_xor(sq_[r], off, 64);
        }
    if (c == 0)
#pragma unroll
        for (int r = 0; r < 4; r++) {
            red[w][4 * g + r][0] = s_[r];
            red[w][4 * g + r][1] = sq_[r];
        }
    __syncthreads();
    float mu[4], rs[4];
#pragma unroll
    for (int r = 0; r < 4; r++) {
        float S = 0.f, Q = 0.f;
#pragma unroll
        for (int ww = 0; ww < 8; ww++) { S += red[ww][4 * g + r][0]; Q += red[ww][4 * g + r][1]; }
        mu[r] = S * (1.f / 256.f);
        rs[r] = rsqrtf(Q * (1.f / 256.f) - mu[r] * mu[r] + 1e-6f);
    }
    float gv0 = gg[col0], bv0 = be[col0], gv1 = gg[col1], bv1 = be[col1];
#pragma unroll
    for (int r = 0; r < 4; r++) {
        int row = rowBase + 4 * g + r;
        float o0 = (vv[0][r] - mu[r]) * rs[r] * gv0 + bv0;
        float o1 = (vv[1][r] - mu[r]) * rs[r] * gv1 + bv1;
        outf[(size_t)row * 256 + col0] = o0;
        outf[(size_t)row * 256 + col1] = o1;
        if (!LAST) {
            outb[(size_t)row * 256 + col0] = f2bf(o0);
            outb[(size_t)row * 256 + col1] = f2bf(o1);
        }
    }
}

// ------------------------------------------------ launch
extern "C" void kernel_launch(void* const* d_in, const int* in_sizes, int n_in,
                              void* d_out, int out_size, void* d_ws, size_t ws_size,
                              hipStream_t stream)
{
    const float* x_in   = (const float*)d_in[0];
    const float* qkv_w  = (const float*)d_in[1];
    const float* proj_w = (const float*)d_in[2];
    const float* proj_b = (const float*)d_in[3];
    const float* w1     = (const float*)d_in[4];
    const float* b1     = (const float*)d_in[5];
    const float* w2     = (const float*)d_in[6];
    const float* b2     = (const float*)d_in[7];
    const float* g1     = (const float*)d_in[8];
    const float* be1    = (const float*)d_in[9];
    const float* g2     = (const float*)d_in[10];
    const float* be2    = (const float*)d_in[11];
    float* outp = (float*)d_out;

    char* p = (char*)d_ws;
    float* xf    = (float*)p;    p += (size_t)Md * Cd * 4;
    short* xb    = (short*)p;    p += (size_t)Md * Cd * 2;
    short* Qb    = (short*)p;    p += (size_t)Md * Cd * 2;
    short* Kb    = (short*)p;    p += (size_t)Md * Cd * 2;
    short* Vtb   = (short*)p;    p += (size_t)Md * Cd * 2;
    unsigned* OPb = (unsigned*)p; p += (size_t)SPLITd * U32d * 512 * 4;
    float* Lsum  = (float*)p;    p += (size_t)SPLITd * U32d * 32 * 4;
    short* qkvT  = (short*)p;    p += (size_t)Ld * 768 * 256 * 2;
    short* projT = (short*)p;    p += (size_t)Ld * 256 * 256 * 2;
    short* w1T   = (short*)p;    p += (size_t)Ld * 256 * 256 * 2;
    short* w2T   = (short*)p;    p += (size_t)Ld * 256 * 256 * 2;

    const float QSCALE = 0.17677669529663687f * 1.4426950408889634f; // 1/sqrt(32)*log2e
    prep_kernel<<<1536 + Md * Cd / 256, 256, 0, stream>>>(
        x_in, qkv_w, proj_w, w1, w2, xf, xb, qkvT, projT, w1T, w2T, QSCALE);

    for (int l = 0; l < Ld; l++) {
        qkv_gemm_kernel<<<dim3(24, 32), 256, 0, stream>>>(
            xb, qkvT + (size_t)l * 768 * 256, Qb, Kb, Vtb);
        attn_part_kernel<<<dim3(16, BHd, SPLITd), 256, 0, stream>>>(Qb, Kb, Vtb, OPb, Lsum);
        proj_ln_kernel<<<Md / 16, 512, 0, stream>>>(
            OPb, Lsum, projT + (size_t)l * 65536, proj_b + l * 256, xf,
            g1 + l * 256, be1 + l * 256, xf, xb);
        if (l == Ld - 1)
            mlp_kernel<1><<<Md / 16, 512, 0, stream>>>(
                xb, w1T + (size_t)l * 65536, b1 + l * 256,
                w2T + (size_t)l * 65536, b2 + l * 256, xf,
                g2 + l * 256, be2 + l * 256, outp, nullptr);
        else
            mlp_kernel<0><<<Md / 16, 512, 0, stream>>>(
                xb, w1T + (size_t)l * 65536, b1 + l * 256,
                w2T + (size_t)l * 65536, b2 + l * 256, xf,
                g2 + l * 256, be2 + l * 256, xf, xb);
    }
}